// Round 1
// baseline (999.457 us; speedup 1.0000x reference)
//
#include <hip/hip_runtime.h>
#include <hip/hip_bf16.h>
#include <math.h>

#define NN 50000
#define NE 600000
#define IN_DIM 7
#define GD 128

// ---------------- CSR build ----------------

__global__ void k_zero_int(int* __restrict__ p, int n) {
    int i = blockIdx.x * blockDim.x + threadIdx.x;
    if (i < n) p[i] = 0;
}

__global__ void k_count(const int* __restrict__ ei, int* __restrict__ deg) {
    int e = blockIdx.x * blockDim.x + threadIdx.x;
    if (e < NE) atomicAdd(&deg[ei[NE + e]], 1);
}

// single-block exclusive scan over 50000 degrees -> off[0..50000]
__global__ void k_scan(const int* __restrict__ deg, int* __restrict__ off) {
    __shared__ int s[256];
    __shared__ int carry;
    if (threadIdx.x == 0) carry = 0;
    __syncthreads();
    for (int base = 0; base < NN; base += 256) {
        int i = base + threadIdx.x;
        int v = (i < NN) ? deg[i] : 0;
        s[threadIdx.x] = v;
        __syncthreads();
        #pragma unroll
        for (int o = 1; o < 256; o <<= 1) {
            int t = (threadIdx.x >= o) ? s[threadIdx.x - o] : 0;
            __syncthreads();
            s[threadIdx.x] += t;
            __syncthreads();
        }
        int incl = s[threadIdx.x];
        if (i < NN) off[i] = carry + (incl - v);
        __syncthreads();
        if (threadIdx.x == 255) carry += incl;
        __syncthreads();
    }
    if (threadIdx.x == 0) off[NN] = carry;
}

__global__ void k_copy_int(const int* __restrict__ a, int* __restrict__ b, int n) {
    int i = blockIdx.x * blockDim.x + threadIdx.x;
    if (i < n) b[i] = a[i];
}

__global__ void k_scatter(const int* __restrict__ ei, int* __restrict__ cur,
                          int* __restrict__ ssrc) {
    int e = blockIdx.x * blockDim.x + threadIdx.x;
    if (e < NE) {
        int s = ei[e];
        int d = ei[NE + e];
        int pos = atomicAdd(&cur[d], 1);
        ssrc[pos] = s;
    }
}

// ---------------- weight prep: Wc[k][0:128]=W1a-W1b, Wc[k][128:256]=W1b ----------------

__global__ void k_wcomb(const float* __restrict__ W1, float* __restrict__ Wc, int d) {
    int i = blockIdx.x * blockDim.x + threadIdx.x;
    if (i < d * 256) {
        int k = i >> 8, c = i & 255;
        float v;
        if (c < 128) v = W1[k * 128 + c] - W1[(k + d) * 128 + c];
        else         v = W1[(k + d) * 128 + (c - 128)];
        Wc[i] = v;
    }
}

// ---------------- layer-0 GEMM: AB[50K x 256] = x[50K x 7] @ Wc[7 x 256] (+b1 on cols<128) ----------------

__global__ __launch_bounds__(256) void k_l0(const float* __restrict__ x,
                                            const float* __restrict__ Wc,
                                            const float* __restrict__ b1,
                                            float* __restrict__ AB) {
    int i = blockIdx.x;
    int c = threadIdx.x;
    __shared__ float xs[IN_DIM];
    if (threadIdx.x < IN_DIM) xs[threadIdx.x] = x[i * IN_DIM + threadIdx.x];
    __syncthreads();
    float acc = (c < 128) ? b1[c] : 0.f;
    #pragma unroll
    for (int k = 0; k < IN_DIM; k++) acc += xs[k] * Wc[k * 256 + c];
    AB[i * 256 + c] = acc;
}

// ---------------- generic K=128 GEMM, 64x64 tile, 4x4 micro-tile ----------------
// BMODE 1: bias[] on global cols < 128, zero elsewhere (AB gemm, NT=256)
// BMODE 2: deg(row) * bias[col]                          (W2 gemm, NT=128)

template <int NT, int BMODE>
__global__ __launch_bounds__(256) void k_gemm128(const float* __restrict__ Hin,
                                                 const float* __restrict__ W,
                                                 const float* __restrict__ bias,
                                                 const int* __restrict__ off,
                                                 float* __restrict__ out, int M) {
    __shared__ float Wl[32][64];
    __shared__ float hT[32][68];
    int tid = threadIdx.x;
    int tc = tid & 15, tr = tid >> 4;
    int m0 = blockIdx.x * 64;
    int c0 = blockIdx.y * 64;
    float acc[4][4];
    #pragma unroll
    for (int i = 0; i < 4; i++)
        #pragma unroll
        for (int j = 0; j < 4; j++) acc[i][j] = 0.f;

    for (int k0 = 0; k0 < 128; k0 += 32) {
        // stage W slice: 32 x 64 (512 float4, 2/thread)
        #pragma unroll
        for (int q = 0; q < 2; q++) {
            int f = tid + q * 256;
            int kk = f >> 4, cq = f & 15;
            float4 wv = *(const float4*)&W[(k0 + kk) * NT + c0 + cq * 4];
            *(float4*)&Wl[kk][cq * 4] = wv;
        }
        // stage h tile transposed: 64 rows x 32 k
        #pragma unroll
        for (int q = 0; q < 2; q++) {
            int f = tid + q * 256;
            int r = f >> 3, kq = f & 7;
            int row = m0 + r;
            float4 hv = make_float4(0.f, 0.f, 0.f, 0.f);
            if (row < M) hv = *(const float4*)&Hin[row * 128 + k0 + kq * 4];
            hT[kq * 4 + 0][r] = hv.x;
            hT[kq * 4 + 1][r] = hv.y;
            hT[kq * 4 + 2][r] = hv.z;
            hT[kq * 4 + 3][r] = hv.w;
        }
        __syncthreads();
        #pragma unroll
        for (int k = 0; k < 32; k++) {
            float4 wv = *(const float4*)&Wl[k][tc * 4];
            float4 av = *(const float4*)&hT[k][tr * 4];
            float a4[4] = {av.x, av.y, av.z, av.w};
            float w4[4] = {wv.x, wv.y, wv.z, wv.w};
            #pragma unroll
            for (int i = 0; i < 4; i++)
                #pragma unroll
                for (int j = 0; j < 4; j++) acc[i][j] += a4[i] * w4[j];
        }
        __syncthreads();
    }
    // epilogue
    #pragma unroll
    for (int i = 0; i < 4; i++) {
        int row = m0 + tr * 4 + i;
        if (row < M) {
            float degf = 0.f;
            if (BMODE == 2) degf = (float)(off[row + 1] - off[row]);
            float4 o;
            float v[4];
            #pragma unroll
            for (int j = 0; j < 4; j++) {
                int gc = c0 + tc * 4 + j;
                float b = 0.f;
                if (BMODE == 1) b = (gc < 128) ? bias[gc] : 0.f;
                if (BMODE == 2) b = degf * bias[gc];
                v[j] = acc[i][j] + b;
            }
            o.x = v[0]; o.y = v[1]; o.z = v[2]; o.w = v[3];
            *(float4*)&out[row * NT + c0 + tc * 4] = o;
        }
    }
}

// ---------------- aggregation: T[i][c] = sum_{e->i} tanh(A[i][c] + B[src][c]) ----------------
// AB layout: AB[i*256 + c] = A, AB[i*256 + 128 + c] = B

__global__ __launch_bounds__(128) void k_agg(const float* __restrict__ AB,
                                             const int* __restrict__ off,
                                             const int* __restrict__ ssrc,
                                             float* __restrict__ T) {
    int i = blockIdx.x;
    int c = threadIdx.x;
    float a = AB[i * 256 + c];
    int s0 = off[i], s1 = off[i + 1];
    float acc = 0.f;
    for (int s = s0; s < s1; s++) {
        int j = ssrc[s];
        acc += tanhf(a + AB[j * 256 + 128 + c]);
    }
    T[i * 128 + c] = acc;
}

// ---------------- output head: out[i][0:3] = H[i] @ Wo + bo ----------------

__global__ __launch_bounds__(256) void k_head(const float* __restrict__ H,
                                              const float* __restrict__ Wo,
                                              const float* __restrict__ bo,
                                              float* __restrict__ out) {
    int lane = threadIdx.x & 63;
    int i = blockIdx.x * 4 + (threadIdx.x >> 6);
    if (i >= NN) return;
    float h0 = H[i * 128 + lane];
    float h1 = H[i * 128 + 64 + lane];
    float p0 = h0 * Wo[lane * 3 + 0] + h1 * Wo[(64 + lane) * 3 + 0];
    float p1 = h0 * Wo[lane * 3 + 1] + h1 * Wo[(64 + lane) * 3 + 1];
    float p2 = h0 * Wo[lane * 3 + 2] + h1 * Wo[(64 + lane) * 3 + 2];
    #pragma unroll
    for (int o = 32; o > 0; o >>= 1) {
        p0 += __shfl_down(p0, o);
        p1 += __shfl_down(p1, o);
        p2 += __shfl_down(p2, o);
    }
    if (lane == 0) {
        out[i * 3 + 0] = p0 + bo[0];
        out[i * 3 + 1] = p1 + bo[1];
        out[i * 3 + 2] = p2 + bo[2];
    }
}

// ---------------- host ----------------

extern "C" void kernel_launch(void* const* d_in, const int* in_sizes, int n_in,
                              void* d_out, int out_size, void* d_ws, size_t ws_size,
                              hipStream_t stream) {
    const float* x    = (const float*)d_in[0];
    const int*   ei   = (const int*)d_in[1];      // [2 x 600000], row 0 = src, row 1 = dst
    const float* W1_0 = (const float*)d_in[2];    // [14 x 128]
    const float* b1_0 = (const float*)d_in[3];
    const float* W2_0 = (const float*)d_in[4];    // [128 x 128]
    const float* b2_0 = (const float*)d_in[5];
    const float* W1s  = (const float*)d_in[6];    // [3 x 256 x 128]
    const float* b1s  = (const float*)d_in[7];    // [3 x 128]
    const float* W2s  = (const float*)d_in[8];    // [3 x 128 x 128]
    const float* b2s  = (const float*)d_in[9];
    const float* Wo   = (const float*)d_in[10];   // [128 x 3]
    const float* bo   = (const float*)d_in[11];
    float* out = (float*)d_out;

    // workspace carve-up (~106 MB)
    float* AB = (float*)d_ws;                 // 50000*256
    float* T  = AB + (size_t)NN * 256;        // 50000*128
    float* H  = T + (size_t)NN * 128;         // 50000*128
    float* Wc = H + (size_t)NN * 128;         // 128*256
    int* deg  = (int*)(Wc + 128 * 256);       // 50000
    int* off  = deg + NN;                     // 50001
    int* cur  = off + (NN + 1);               // 50000
    int* ssrc = cur + NN;                     // 600000

    const int B256 = 256;
    int gN  = (NN + B256 - 1) / B256;
    int gE  = (NE + B256 - 1) / B256;

    // ---- CSR by dst (rebuilt every call; ws is poisoned between calls) ----
    k_zero_int<<<gN, B256, 0, stream>>>(deg, NN);
    k_count<<<gE, B256, 0, stream>>>(ei, deg);
    k_scan<<<1, B256, 0, stream>>>(deg, off);
    k_copy_int<<<gN, B256, 0, stream>>>(off, cur, NN);
    k_scatter<<<gE, B256, 0, stream>>>(ei, cur, ssrc);

    dim3 g1((NN + 63) / 64, 4);   // NT=256 gemm
    dim3 g2((NN + 63) / 64, 2);   // NT=128 gemm

    // ---- layer 0 (in_dim = 7) ----
    k_wcomb<<<(IN_DIM * 256 + 255) / 256, B256, 0, stream>>>(W1_0, Wc, IN_DIM);
    k_l0<<<NN, 256, 0, stream>>>(x, Wc, b1_0, AB);
    k_agg<<<NN, 128, 0, stream>>>(AB, off, ssrc, T);
    k_gemm128<128, 2><<<g2, B256, 0, stream>>>(T, W2_0, b2_0, off, H, NN);

    // ---- layers 1..3 (dim 128) ----
    for (int l = 0; l < 3; l++) {
        const float* W1 = W1s + (size_t)l * 256 * 128;
        const float* b1 = b1s + (size_t)l * 128;
        const float* W2 = W2s + (size_t)l * 128 * 128;
        const float* b2 = b2s + (size_t)l * 128;
        k_wcomb<<<(128 * 256 + 255) / 256, B256, 0, stream>>>(W1, Wc, 128);
        k_gemm128<256, 1><<<g1, B256, 0, stream>>>(H, Wc, b1, nullptr, AB, NN);
        k_agg<<<NN, 128, 0, stream>>>(AB, off, ssrc, T);
        k_gemm128<128, 2><<<g2, B256, 0, stream>>>(T, W2, b2, off, H, NN);
    }

    // ---- output head ----
    k_head<<<(NN + 3) / 4, B256, 0, stream>>>(H, Wo, bo, out);
}

// Round 2
// 758.046 us; speedup vs baseline: 1.3185x; 1.3185x over previous
//
#include <hip/hip_runtime.h>
#include <hip/hip_bf16.h>
#include <math.h>

#define NN 50000
#define NE 600000
#define IN_DIM 7
#define GD 128
#define SCAN_B ((NN + 255) / 256)   // 196 blocks

// ---------------- CSR build ----------------

__global__ void k_zero_int(int* __restrict__ p, int n) {
    int i = blockIdx.x * blockDim.x + threadIdx.x;
    if (i < n) p[i] = 0;
}

__global__ void k_count(const int* __restrict__ ei, int* __restrict__ deg) {
    int e = blockIdx.x * blockDim.x + threadIdx.x;
    if (e < NE) atomicAdd(&deg[ei[NE + e]], 1);
}

// hierarchical scan, phase 1: per-block exclusive scan + block sums
__global__ __launch_bounds__(256) void k_scan1(const int* __restrict__ deg,
                                               int* __restrict__ off,
                                               int* __restrict__ part) {
    __shared__ int s[256];
    int i = blockIdx.x * 256 + threadIdx.x;
    int v = (i < NN) ? deg[i] : 0;
    s[threadIdx.x] = v;
    __syncthreads();
    #pragma unroll
    for (int o = 1; o < 256; o <<= 1) {
        int t = (threadIdx.x >= o) ? s[threadIdx.x - o] : 0;
        __syncthreads();
        s[threadIdx.x] += t;
        __syncthreads();
    }
    if (i < NN) off[i] = s[threadIdx.x] - v;
    if (threadIdx.x == 255) part[blockIdx.x] = s[255];
}

// phase 2: scan the 196 block sums (single tiny block), write grand total to off[NN]
__global__ __launch_bounds__(256) void k_scan2(int* __restrict__ part,
                                               int* __restrict__ off) {
    __shared__ int s[256];
    int v = (threadIdx.x < SCAN_B) ? part[threadIdx.x] : 0;
    s[threadIdx.x] = v;
    __syncthreads();
    #pragma unroll
    for (int o = 1; o < 256; o <<= 1) {
        int t = (threadIdx.x >= o) ? s[threadIdx.x - o] : 0;
        __syncthreads();
        s[threadIdx.x] += t;
        __syncthreads();
    }
    if (threadIdx.x < SCAN_B) part[threadIdx.x] = s[threadIdx.x] - v;
    if (threadIdx.x == 255) off[NN] = s[255];
}

// phase 3: add block offsets; also produce cur[] (scatter cursor copy)
__global__ __launch_bounds__(256) void k_scan3(int* __restrict__ off,
                                               const int* __restrict__ part,
                                               int* __restrict__ cur) {
    int i = blockIdx.x * 256 + threadIdx.x;
    if (i < NN) {
        int v = off[i] + part[blockIdx.x];
        off[i] = v;
        cur[i] = v;
    }
}

__global__ void k_scatter(const int* __restrict__ ei, int* __restrict__ cur,
                          int* __restrict__ ssrc) {
    int e = blockIdx.x * blockDim.x + threadIdx.x;
    if (e < NE) {
        int s = ei[e];
        int d = ei[NE + e];
        int pos = atomicAdd(&cur[d], 1);
        ssrc[pos] = s;
    }
}

// ---------------- weight prep: Wc[k][0:128]=W1a-W1b, Wc[k][128:256]=W1b ----------------

__global__ void k_wcomb(const float* __restrict__ W1, float* __restrict__ Wc, int d) {
    int i = blockIdx.x * blockDim.x + threadIdx.x;
    if (i < d * 256) {
        int k = i >> 8, c = i & 255;
        float v;
        if (c < 128) v = W1[k * 128 + c] - W1[(k + d) * 128 + c];
        else         v = W1[(k + d) * 128 + (c - 128)];
        Wc[i] = v;
    }
}

// ---------------- layer-0 GEMM: AB[50K x 256] = x[50K x 7] @ Wc[7 x 256] (+b1 on cols<128) ----------------

__global__ __launch_bounds__(256) void k_l0(const float* __restrict__ x,
                                            const float* __restrict__ Wc,
                                            const float* __restrict__ b1,
                                            float* __restrict__ AB) {
    int i = blockIdx.x;
    int c = threadIdx.x;
    __shared__ float xs[IN_DIM];
    if (threadIdx.x < IN_DIM) xs[threadIdx.x] = x[i * IN_DIM + threadIdx.x];
    __syncthreads();
    float acc = (c < 128) ? b1[c] : 0.f;
    #pragma unroll
    for (int k = 0; k < IN_DIM; k++) acc += xs[k] * Wc[k * 256 + c];
    AB[i * 256 + c] = acc;
}

// ---------------- generic K=128 GEMM, 64x64 tile, 4x4 micro-tile ----------------
// BMODE 1: bias[] on global cols < 128, zero elsewhere (AB gemm, NT=256)
// BMODE 2: deg(row) * bias[col]                          (W2 gemm, NT=128)

template <int NT, int BMODE>
__global__ __launch_bounds__(256) void k_gemm128(const float* __restrict__ Hin,
                                                 const float* __restrict__ W,
                                                 const float* __restrict__ bias,
                                                 const int* __restrict__ off,
                                                 float* __restrict__ out, int M) {
    __shared__ float Wl[32][64];
    __shared__ float hT[32][68];
    int tid = threadIdx.x;
    int tc = tid & 15, tr = tid >> 4;
    int m0 = blockIdx.x * 64;
    int c0 = blockIdx.y * 64;
    float acc[4][4];
    #pragma unroll
    for (int i = 0; i < 4; i++)
        #pragma unroll
        for (int j = 0; j < 4; j++) acc[i][j] = 0.f;

    for (int k0 = 0; k0 < 128; k0 += 32) {
        #pragma unroll
        for (int q = 0; q < 2; q++) {
            int f = tid + q * 256;
            int kk = f >> 4, cq = f & 15;
            float4 wv = *(const float4*)&W[(k0 + kk) * NT + c0 + cq * 4];
            *(float4*)&Wl[kk][cq * 4] = wv;
        }
        #pragma unroll
        for (int q = 0; q < 2; q++) {
            int f = tid + q * 256;
            int r = f >> 3, kq = f & 7;
            int row = m0 + r;
            float4 hv = make_float4(0.f, 0.f, 0.f, 0.f);
            if (row < M) hv = *(const float4*)&Hin[row * 128 + k0 + kq * 4];
            hT[kq * 4 + 0][r] = hv.x;
            hT[kq * 4 + 1][r] = hv.y;
            hT[kq * 4 + 2][r] = hv.z;
            hT[kq * 4 + 3][r] = hv.w;
        }
        __syncthreads();
        #pragma unroll
        for (int k = 0; k < 32; k++) {
            float4 wv = *(const float4*)&Wl[k][tc * 4];
            float4 av = *(const float4*)&hT[k][tr * 4];
            float a4[4] = {av.x, av.y, av.z, av.w};
            float w4[4] = {wv.x, wv.y, wv.z, wv.w};
            #pragma unroll
            for (int i = 0; i < 4; i++)
                #pragma unroll
                for (int j = 0; j < 4; j++) acc[i][j] += a4[i] * w4[j];
        }
        __syncthreads();
    }
    #pragma unroll
    for (int i = 0; i < 4; i++) {
        int row = m0 + tr * 4 + i;
        if (row < M) {
            float degf = 0.f;
            if (BMODE == 2) degf = (float)(off[row + 1] - off[row]);
            float4 o;
            float v[4];
            #pragma unroll
            for (int j = 0; j < 4; j++) {
                int gc = c0 + tc * 4 + j;
                float b = 0.f;
                if (BMODE == 1) b = (gc < 128) ? bias[gc] : 0.f;
                if (BMODE == 2) b = degf * bias[gc];
                v[j] = acc[i][j] + b;
            }
            o.x = v[0]; o.y = v[1]; o.z = v[2]; o.w = v[3];
            *(float4*)&out[row * NT + c0 + tc * 4] = o;
        }
    }
}

// ---------------- aggregation: T[i][c] = sum_{e->i} tanh(A[i][c] + B[src][c]) ----------------

__device__ __forceinline__ float tanh_fast(float x) {
    // tanh(x) = sign(x) * (1 - 2/(e^{2|x|}+1)); saturates to +-1, no NaN at overflow
    float ax = __builtin_fabsf(x);
    float e = __expf(2.f * ax);
    float inv = __builtin_amdgcn_rcpf(e + 1.f);
    float r = 1.f - 2.f * inv;
    return __builtin_copysignf(r, x);
}

__global__ __launch_bounds__(128) void k_agg(const float* __restrict__ AB,
                                             const int* __restrict__ off,
                                             const int* __restrict__ ssrc,
                                             float* __restrict__ T) {
    int i = blockIdx.x;
    int c = threadIdx.x;
    float a = AB[i * 256 + c];
    int s0 = off[i], s1 = off[i + 1];
    float acc = 0.f;
    for (int s = s0; s < s1; s++) {
        int j = ssrc[s];
        acc += tanh_fast(a + AB[j * 256 + 128 + c]);
    }
    T[i * 128 + c] = acc;
}

// ---------------- output head: out[i][0:3] = H[i] @ Wo + bo ----------------

__global__ __launch_bounds__(256) void k_head(const float* __restrict__ H,
                                              const float* __restrict__ Wo,
                                              const float* __restrict__ bo,
                                              float* __restrict__ out) {
    int lane = threadIdx.x & 63;
    int i = blockIdx.x * 4 + (threadIdx.x >> 6);
    if (i >= NN) return;
    float h0 = H[i * 128 + lane];
    float h1 = H[i * 128 + 64 + lane];
    float p0 = h0 * Wo[lane * 3 + 0] + h1 * Wo[(64 + lane) * 3 + 0];
    float p1 = h0 * Wo[lane * 3 + 1] + h1 * Wo[(64 + lane) * 3 + 1];
    float p2 = h0 * Wo[lane * 3 + 2] + h1 * Wo[(64 + lane) * 3 + 2];
    #pragma unroll
    for (int o = 32; o > 0; o >>= 1) {
        p0 += __shfl_down(p0, o);
        p1 += __shfl_down(p1, o);
        p2 += __shfl_down(p2, o);
    }
    if (lane == 0) {
        out[i * 3 + 0] = p0 + bo[0];
        out[i * 3 + 1] = p1 + bo[1];
        out[i * 3 + 2] = p2 + bo[2];
    }
}

// ---------------- host ----------------

extern "C" void kernel_launch(void* const* d_in, const int* in_sizes, int n_in,
                              void* d_out, int out_size, void* d_ws, size_t ws_size,
                              hipStream_t stream) {
    const float* x    = (const float*)d_in[0];
    const int*   ei   = (const int*)d_in[1];
    const float* W1_0 = (const float*)d_in[2];
    const float* b1_0 = (const float*)d_in[3];
    const float* W2_0 = (const float*)d_in[4];
    const float* b2_0 = (const float*)d_in[5];
    const float* W1s  = (const float*)d_in[6];
    const float* b1s  = (const float*)d_in[7];
    const float* W2s  = (const float*)d_in[8];
    const float* b2s  = (const float*)d_in[9];
    const float* Wo   = (const float*)d_in[10];
    const float* bo   = (const float*)d_in[11];
    float* out = (float*)d_out;

    float* AB = (float*)d_ws;                 // 50000*256
    float* T  = AB + (size_t)NN * 256;        // 50000*128
    float* H  = T + (size_t)NN * 128;         // 50000*128
    float* Wc = H + (size_t)NN * 128;         // 128*256
    int* deg  = (int*)(Wc + 128 * 256);       // 50000
    int* off  = deg + NN;                     // 50001
    int* cur  = off + (NN + 1);               // 50000
    int* ssrc = cur + NN;                     // 600000
    int* part = ssrc + NE;                    // 256

    const int B256 = 256;
    int gN  = (NN + B256 - 1) / B256;
    int gE  = (NE + B256 - 1) / B256;

    // ---- CSR by dst (rebuilt every call; ws is poisoned between calls) ----
    k_zero_int<<<gN, B256, 0, stream>>>(deg, NN);
    k_count<<<gE, B256, 0, stream>>>(ei, deg);
    k_scan1<<<SCAN_B, B256, 0, stream>>>(deg, off, part);
    k_scan2<<<1, B256, 0, stream>>>(part, off);
    k_scan3<<<SCAN_B, B256, 0, stream>>>(off, part, cur);
    k_scatter<<<gE, B256, 0, stream>>>(ei, cur, ssrc);

    dim3 g1((NN + 63) / 64, 4);   // NT=256 gemm
    dim3 g2((NN + 63) / 64, 2);   // NT=128 gemm

    // ---- layer 0 (in_dim = 7) ----
    k_wcomb<<<(IN_DIM * 256 + 255) / 256, B256, 0, stream>>>(W1_0, Wc, IN_DIM);
    k_l0<<<NN, 256, 0, stream>>>(x, Wc, b1_0, AB);
    k_agg<<<NN, 128, 0, stream>>>(AB, off, ssrc, T);
    k_gemm128<128, 2><<<g2, B256, 0, stream>>>(T, W2_0, b2_0, off, H, NN);

    // ---- layers 1..3 (dim 128) ----
    for (int l = 0; l < 3; l++) {
        const float* W1 = W1s + (size_t)l * 256 * 128;
        const float* b1 = b1s + (size_t)l * 128;
        const float* W2 = W2s + (size_t)l * 128 * 128;
        const float* b2 = b2s + (size_t)l * 128;
        k_wcomb<<<(128 * 256 + 255) / 256, B256, 0, stream>>>(W1, Wc, 128);
        k_gemm128<256, 1><<<g1, B256, 0, stream>>>(H, Wc, b1, nullptr, AB, NN);
        k_agg<<<NN, 128, 0, stream>>>(AB, off, ssrc, T);
        k_gemm128<128, 2><<<g2, B256, 0, stream>>>(T, W2, b2, off, H, NN);
    }

    // ---- output head ----
    k_head<<<(NN + 3) / 4, B256, 0, stream>>>(H, Wo, bo, out);
}

// Round 3
// 470.625 us; speedup vs baseline: 2.1237x; 1.6107x over previous
//
#include <hip/hip_runtime.h>
#include <hip/hip_bf16.h>
#include <math.h>

#define NN 50000
#define NE 600000
#define IN_DIM 7
#define SCAN_B ((NN + 255) / 256)   // 196 blocks

typedef short short8 __attribute__((ext_vector_type(8)));
typedef float f32x4  __attribute__((ext_vector_type(4)));
typedef unsigned int uint;

// ---------------- CSR build ----------------

__global__ void k_zero_int(int* __restrict__ p, int n) {
    int i = blockIdx.x * blockDim.x + threadIdx.x;
    if (i < n) p[i] = 0;
}

__global__ void k_count(const int* __restrict__ ei, int* __restrict__ deg) {
    int e = blockIdx.x * blockDim.x + threadIdx.x;
    if (e < NE) atomicAdd(&deg[ei[NE + e]], 1);
}

__global__ __launch_bounds__(256) void k_scan1(const int* __restrict__ deg,
                                               int* __restrict__ off,
                                               int* __restrict__ part,
                                               float* __restrict__ degv) {
    __shared__ int s[256];
    int i = blockIdx.x * 256 + threadIdx.x;
    int v = (i < NN) ? deg[i] : 0;
    s[threadIdx.x] = v;
    __syncthreads();
    #pragma unroll
    for (int o = 1; o < 256; o <<= 1) {
        int t = (threadIdx.x >= o) ? s[threadIdx.x - o] : 0;
        __syncthreads();
        s[threadIdx.x] += t;
        __syncthreads();
    }
    if (i < NN) { off[i] = s[threadIdx.x] - v; degv[i] = (float)v; }
    if (threadIdx.x == 255) part[blockIdx.x] = s[255];
}

__global__ __launch_bounds__(256) void k_scan2(int* __restrict__ part,
                                               int* __restrict__ off) {
    __shared__ int s[256];
    int v = (threadIdx.x < SCAN_B) ? part[threadIdx.x] : 0;
    s[threadIdx.x] = v;
    __syncthreads();
    #pragma unroll
    for (int o = 1; o < 256; o <<= 1) {
        int t = (threadIdx.x >= o) ? s[threadIdx.x - o] : 0;
        __syncthreads();
        s[threadIdx.x] += t;
        __syncthreads();
    }
    if (threadIdx.x < SCAN_B) part[threadIdx.x] = s[threadIdx.x] - v;
    if (threadIdx.x == 255) off[NN] = s[255];
}

__global__ __launch_bounds__(256) void k_scan3(int* __restrict__ off,
                                               const int* __restrict__ part,
                                               int* __restrict__ cur) {
    int i = blockIdx.x * 256 + threadIdx.x;
    if (i < NN) {
        int v = off[i] + part[blockIdx.x];
        off[i] = v;
        cur[i] = v;
    }
}

__global__ void k_scatter(const int* __restrict__ ei, int* __restrict__ cur,
                          int* __restrict__ ssrc) {
    int e = blockIdx.x * blockDim.x + threadIdx.x;
    if (e < NE) {
        int s = ei[e];
        int d = ei[NE + e];
        int pos = atomicAdd(&cur[d], 1);
        ssrc[pos] = s;
    }
}

// ---------------- weight prep ----------------
// Wc[k][0:128]=W1a-W1b, Wc[k][128:256]=W1b  (fp32, k in [0,d))
__global__ void k_wcomb(const float* __restrict__ W1, float* __restrict__ Wc, int d) {
    int i = blockIdx.x * blockDim.x + threadIdx.x;
    if (i < d * 256) {
        int k = i >> 8, c = i & 255;
        float v;
        if (c < 128) v = W1[k * 128 + c] - W1[(k + d) * 128 + c];
        else         v = W1[(k + d) * 128 + (c - 128)];
        Wc[i] = v;
    }
}

// Wt[c][k] (bf16, col-major) = (W2p @ Wc)[k][c]   -- fused next-layer weight
__global__ __launch_bounds__(128) void k_fuse(const float* __restrict__ W2p,
                                              const float* __restrict__ Wc,
                                              __hip_bfloat16* __restrict__ Wt) {
    int c = blockIdx.x;       // 0..255
    int k = threadIdx.x;      // 0..127
    float acc = 0.f;
    for (int m = 0; m < 128; m++) acc += W2p[k * 128 + m] * Wc[m * 256 + c];
    Wt[c * 128 + k] = __float2bfloat16(acc);
}

// dvec[c] = (b2p @ Wc)[c]; bcat[c] = c<128 ? b1[c] : 0
__global__ void k_bias(const float* __restrict__ b2p, const float* __restrict__ Wc,
                       const float* __restrict__ b1l, float* __restrict__ dvec,
                       float* __restrict__ bcat) {
    int c = threadIdx.x;  // 256
    float acc = 0.f;
    for (int m = 0; m < 128; m++) acc += b2p[m] * Wc[m * 256 + c];
    dvec[c] = acc;
    bcat[c] = (c < 128) ? b1l[c] : 0.f;
}

// Wf[k][r] = (W2_last @ Wo)[k][r]; bfh[r] = (b2_last @ Wo)[r]
__global__ __launch_bounds__(128) void k_fuse_head(const float* __restrict__ W2l,
                                                   const float* __restrict__ Wo,
                                                   const float* __restrict__ b2l,
                                                   float* __restrict__ Wf,
                                                   float* __restrict__ bfh) {
    int k = threadIdx.x;
    #pragma unroll
    for (int r = 0; r < 3; r++) {
        float acc = 0.f;
        for (int m = 0; m < 128; m++) acc += W2l[k * 128 + m] * Wo[m * 3 + r];
        Wf[k * 3 + r] = acc;
    }
    if (k < 3) {
        float acc = 0.f;
        for (int m = 0; m < 128; m++) acc += b2l[m] * Wo[m * 3 + k];
        bfh[k] = acc;
    }
}

// ---------------- layer-0: AB[50K x 256] = x[50K x 7] @ Wc + b1cat (bf16 out) ----------------

__global__ __launch_bounds__(256) void k_l0(const float* __restrict__ x,
                                            const float* __restrict__ Wc,
                                            const float* __restrict__ b1,
                                            __hip_bfloat16* __restrict__ AB) {
    int i = blockIdx.x;
    int c = threadIdx.x;
    __shared__ float xs[IN_DIM];
    if (threadIdx.x < IN_DIM) xs[threadIdx.x] = x[i * IN_DIM + threadIdx.x];
    __syncthreads();
    float acc = (c < 128) ? b1[c] : 0.f;
    #pragma unroll
    for (int k = 0; k < IN_DIM; k++) acc += xs[k] * Wc[k * 256 + c];
    AB[i * 256 + c] = __float2bfloat16(acc);
}

// ---------------- fused MFMA GEMM: AB = T[M x 128] @ Wt^T + deg*dvec + bcat ----------------
// Wt is [256 cols][128 k] bf16 col-major. Block: 64 rows x 256 cols, 4 waves (one 64-col strip each).

__global__ __launch_bounds__(256) void k_gemm_ab(const __hip_bfloat16* __restrict__ Tin,
                                                 const __hip_bfloat16* __restrict__ Wt,
                                                 const float* __restrict__ dvec,
                                                 const float* __restrict__ bcat,
                                                 const float* __restrict__ degv,
                                                 __hip_bfloat16* __restrict__ ABout) {
    __shared__ short Tl[64 * 136];   // +8 shorts pad per row -> conflict-free ds_read_b128
    __shared__ float degl[64];
    int t = threadIdx.x;
    int m0 = blockIdx.x * 64;
    const short* Ts = (const short*)Tin;
    const short* Ws = (const short*)Wt;

    #pragma unroll
    for (int it = 0; it < 4; it++) {
        int idx = t + it * 256;
        int row = idx >> 4, seg = idx & 15;
        int gr = m0 + row;
        short8 v = {0, 0, 0, 0, 0, 0, 0, 0};
        if (gr < NN) v = *(const short8*)&Ts[gr * 128 + seg * 8];
        *(short8*)&Tl[row * 136 + seg * 8] = v;
    }
    if (t < 64) degl[t] = (m0 + t < NN) ? degv[m0 + t] : 0.f;
    __syncthreads();

    int lane = t & 63;
    int wv = t >> 6;
    int l15 = lane & 15, quad = lane >> 4;

    short8 a[4][4];
    #pragma unroll
    for (int rt = 0; rt < 4; rt++)
        #pragma unroll
        for (int ks = 0; ks < 4; ks++)
            a[rt][ks] = *(const short8*)&Tl[(rt * 16 + l15) * 136 + ks * 32 + quad * 8];

    int c0 = wv * 64;
    #pragma unroll
    for (int ct = 0; ct < 4; ct++) {
        int ccol = c0 + ct * 16 + l15;
        short8 b[4];
        #pragma unroll
        for (int ks = 0; ks < 4; ks++)
            b[ks] = *(const short8*)&Ws[ccol * 128 + ks * 32 + quad * 8];
        float bc = bcat[ccol], dv = dvec[ccol];
        #pragma unroll
        for (int rt = 0; rt < 4; rt++) {
            f32x4 acc = {0.f, 0.f, 0.f, 0.f};
            #pragma unroll
            for (int ks = 0; ks < 4; ks++)
                acc = __builtin_amdgcn_mfma_f32_16x16x32_bf16(a[rt][ks], b[ks], acc, 0, 0, 0);
            #pragma unroll
            for (int r = 0; r < 4; r++) {
                int row = rt * 16 + quad * 4 + r;
                int grow = m0 + row;
                if (grow < NN) {
                    float v = acc[r] + degl[row] * dv + bc;
                    ABout[(size_t)grow * 256 + ccol] = __float2bfloat16(v);
                }
            }
        }
    }
}

// ---------------- aggregation: T[i][c] = sum_e tanh(A[i][c] + B[src][c]) (bf16 in/out) ----------------

__device__ __forceinline__ float tanh_fast(float x) {
    float ax = __builtin_fabsf(x);
    float e = __expf(2.f * ax);
    float inv = __builtin_amdgcn_rcpf(e + 1.f);
    float r = 1.f - 2.f * inv;
    return __builtin_copysignf(r, x);
}

__device__ __forceinline__ float bf_lo(uint u) { return __uint_as_float(u << 16); }
__device__ __forceinline__ float bf_hi(uint u) { return __uint_as_float(u & 0xffff0000u); }

__global__ __launch_bounds__(256) void k_agg(const __hip_bfloat16* __restrict__ AB,
                                             const int* __restrict__ off,
                                             const int* __restrict__ ssrc,
                                             __hip_bfloat16* __restrict__ T) {
    int t = threadIdx.x;
    int i = blockIdx.x * 4 + (t >> 6);   // one wave per node
    int c2 = t & 63;                     // channels 2*c2, 2*c2+1
    const uint* ABu = (const uint*)AB;   // 128 uints per row: A=[0,64), B=[64,128)
    uint au = ABu[i * 128 + c2];
    float a0 = bf_lo(au), a1 = bf_hi(au);
    int s0 = off[i], s1 = off[i + 1];
    float acc0 = 0.f, acc1 = 0.f;
    int s = s0;
    for (; s + 4 <= s1; s += 4) {
        int j0 = ssrc[s], j1 = ssrc[s + 1], j2 = ssrc[s + 2], j3 = ssrc[s + 3];
        uint b0 = ABu[j0 * 128 + 64 + c2];
        uint b1 = ABu[j1 * 128 + 64 + c2];
        uint b2 = ABu[j2 * 128 + 64 + c2];
        uint b3 = ABu[j3 * 128 + 64 + c2];
        acc0 += tanh_fast(a0 + bf_lo(b0)); acc1 += tanh_fast(a1 + bf_hi(b0));
        acc0 += tanh_fast(a0 + bf_lo(b1)); acc1 += tanh_fast(a1 + bf_hi(b1));
        acc0 += tanh_fast(a0 + bf_lo(b2)); acc1 += tanh_fast(a1 + bf_hi(b2));
        acc0 += tanh_fast(a0 + bf_lo(b3)); acc1 += tanh_fast(a1 + bf_hi(b3));
    }
    for (; s < s1; s++) {
        uint b = ABu[ssrc[s] * 128 + 64 + c2];
        acc0 += tanh_fast(a0 + bf_lo(b)); acc1 += tanh_fast(a1 + bf_hi(b));
    }
    __hip_bfloat162 p = __float22bfloat162_rn(make_float2(acc0, acc1));
    ((__hip_bfloat162*)T)[i * 64 + c2] = p;
}

// ---------------- fused head: out[i][r] = T4[i] @ Wf + deg_i*bfh[r] + bo[r] ----------------

__global__ __launch_bounds__(256) void k_headf(const __hip_bfloat16* __restrict__ T,
                                               const float* __restrict__ Wf,
                                               const float* __restrict__ bfh,
                                               const float* __restrict__ bo,
                                               const float* __restrict__ degv,
                                               float* __restrict__ out) {
    int t = threadIdx.x;
    int i = blockIdx.x * 4 + (t >> 6);
    int c2 = t & 63;
    uint u = ((const uint*)T)[i * 64 + c2];
    float f0 = bf_lo(u), f1 = bf_hi(u);
    float p0 = f0 * Wf[(2 * c2) * 3 + 0] + f1 * Wf[(2 * c2 + 1) * 3 + 0];
    float p1 = f0 * Wf[(2 * c2) * 3 + 1] + f1 * Wf[(2 * c2 + 1) * 3 + 1];
    float p2 = f0 * Wf[(2 * c2) * 3 + 2] + f1 * Wf[(2 * c2 + 1) * 3 + 2];
    #pragma unroll
    for (int o = 32; o > 0; o >>= 1) {
        p0 += __shfl_down(p0, o);
        p1 += __shfl_down(p1, o);
        p2 += __shfl_down(p2, o);
    }
    if (c2 == 0) {
        float d = degv[i];
        out[i * 3 + 0] = p0 + d * bfh[0] + bo[0];
        out[i * 3 + 1] = p1 + d * bfh[1] + bo[1];
        out[i * 3 + 2] = p2 + d * bfh[2] + bo[2];
    }
}

// ---------------- host ----------------

extern "C" void kernel_launch(void* const* d_in, const int* in_sizes, int n_in,
                              void* d_out, int out_size, void* d_ws, size_t ws_size,
                              hipStream_t stream) {
    const float* x    = (const float*)d_in[0];
    const int*   ei   = (const int*)d_in[1];
    const float* W1_0 = (const float*)d_in[2];
    const float* b1_0 = (const float*)d_in[3];
    const float* W2_0 = (const float*)d_in[4];
    const float* b2_0 = (const float*)d_in[5];
    const float* W1s  = (const float*)d_in[6];
    const float* b1s  = (const float*)d_in[7];
    const float* W2s  = (const float*)d_in[8];
    const float* b2s  = (const float*)d_in[9];
    const float* Wo   = (const float*)d_in[10];
    const float* bo   = (const float*)d_in[11];
    float* out = (float*)d_out;

    // byte-carved workspace, 256B aligned chunks
    char* w = (char*)d_ws;
    __hip_bfloat16* AB = (__hip_bfloat16*)w;              w += (size_t)NN * 256 * 2;     // 25.6 MB
    __hip_bfloat16* T  = (__hip_bfloat16*)w;              w += (size_t)NN * 128 * 2;     // 12.8 MB
    float* Wc   = (float*)w;                              w += 128 * 256 * 4;
    __hip_bfloat16* Wt = (__hip_bfloat16*)w;              w += 256 * 128 * 2;
    float* Wf   = (float*)w;                              w += 2048;
    float* bfh  = (float*)w;                              w += 256;
    float* dvec = (float*)w;                              w += 1024;
    float* bcat = (float*)w;                              w += 1024;
    float* degv = (float*)w;                              w += (size_t)NN * 4;
    int* deg    = (int*)w;                                w += (size_t)NN * 4;
    int* off    = (int*)w;                                w += (size_t)(NN + 4) * 4;
    int* cur    = (int*)w;                                w += (size_t)NN * 4;
    int* ssrc   = (int*)w;                                w += (size_t)NE * 4;
    int* part   = (int*)w;                                w += 1024;

    const int B256 = 256;
    int gN = (NN + B256 - 1) / B256;
    int gE = (NE + B256 - 1) / B256;
    int gGemm = (NN + 63) / 64;   // 782
    int gAgg = NN / 4;            // 12500

    // ---- CSR by dst ----
    k_zero_int<<<gN, B256, 0, stream>>>(deg, NN);
    k_count<<<gE, B256, 0, stream>>>(ei, deg);
    k_scan1<<<SCAN_B, B256, 0, stream>>>(deg, off, part, degv);
    k_scan2<<<1, B256, 0, stream>>>(part, off);
    k_scan3<<<SCAN_B, B256, 0, stream>>>(off, part, cur);
    k_scatter<<<gE, B256, 0, stream>>>(ei, cur, ssrc);

    // ---- layer 0 ----
    k_wcomb<<<(IN_DIM * 256 + 255) / 256, B256, 0, stream>>>(W1_0, Wc, IN_DIM);
    k_l0<<<NN, 256, 0, stream>>>(x, Wc, b1_0, AB);
    k_agg<<<gAgg, B256, 0, stream>>>(AB, off, ssrc, T);

    // ---- fused layers g = 1..3: AB = T @ (W2_prev @ Wc_g) + deg*(b2_prev@Wc_g) + b1cat ----
    for (int g = 1; g <= 3; g++) {
        const float* W1  = W1s + (size_t)(g - 1) * 256 * 128;
        const float* b1l = b1s + (size_t)(g - 1) * 128;
        const float* W2p = (g == 1) ? W2_0 : W2s + (size_t)(g - 2) * 128 * 128;
        const float* b2p = (g == 1) ? b2_0 : b2s + (size_t)(g - 2) * 128;
        k_wcomb<<<128, B256, 0, stream>>>(W1, Wc, 128);
        k_fuse<<<256, 128, 0, stream>>>(W2p, Wc, Wt);
        k_bias<<<1, 256, 0, stream>>>(b2p, Wc, b1l, dvec, bcat);
        k_gemm_ab<<<gGemm, B256, 0, stream>>>(T, Wt, dvec, bcat, degv, AB);
        k_agg<<<gAgg, B256, 0, stream>>>(AB, off, ssrc, T);
    }

    // ---- fused head: out = T @ (W2_3 @ Wo) + deg*(b2_3@Wo) + bo ----
    k_fuse_head<<<1, 128, 0, stream>>>(W2s + (size_t)2 * 128 * 128, Wo,
                                       b2s + (size_t)2 * 128, Wf, bfh);
    k_headf<<<gAgg, B256, 0, stream>>>(T, Wf, bfh, bo, degv, out);
}

// Round 5
// 439.192 us; speedup vs baseline: 2.2757x; 1.0716x over previous
//
#include <hip/hip_runtime.h>
#include <hip/hip_fp16.h>
#include <math.h>

#define NN 50000
#define NE 600000
#define IN_DIM 7
#define SCAN_B ((NN + 255) / 256)   // 196 blocks

typedef _Float16 half8 __attribute__((ext_vector_type(8)));
typedef short short8 __attribute__((ext_vector_type(8)));
typedef float f32x4  __attribute__((ext_vector_type(4)));
typedef unsigned int uint;

// ---------------- CSR build ----------------

__global__ void k_zero_int(int* __restrict__ p, int n) {
    int i = blockIdx.x * blockDim.x + threadIdx.x;
    if (i < n) p[i] = 0;
}

__global__ void k_count(const int* __restrict__ ei, int* __restrict__ deg) {
    int e = blockIdx.x * blockDim.x + threadIdx.x;
    if (e < NE) atomicAdd(&deg[ei[NE + e]], 1);
}

__global__ __launch_bounds__(256) void k_scan1(const int* __restrict__ deg,
                                               int* __restrict__ off,
                                               int* __restrict__ part,
                                               float* __restrict__ degv) {
    __shared__ int s[256];
    int i = blockIdx.x * 256 + threadIdx.x;
    int v = (i < NN) ? deg[i] : 0;
    s[threadIdx.x] = v;
    __syncthreads();
    #pragma unroll
    for (int o = 1; o < 256; o <<= 1) {
        int t = (threadIdx.x >= o) ? s[threadIdx.x - o] : 0;
        __syncthreads();
        s[threadIdx.x] += t;
        __syncthreads();
    }
    if (i < NN) { off[i] = s[threadIdx.x] - v; degv[i] = (float)v; }
    if (threadIdx.x == 255) part[blockIdx.x] = s[255];
}

__global__ __launch_bounds__(256) void k_scan2(int* __restrict__ part,
                                               int* __restrict__ off) {
    __shared__ int s[256];
    int v = (threadIdx.x < SCAN_B) ? part[threadIdx.x] : 0;
    s[threadIdx.x] = v;
    __syncthreads();
    #pragma unroll
    for (int o = 1; o < 256; o <<= 1) {
        int t = (threadIdx.x >= o) ? s[threadIdx.x - o] : 0;
        __syncthreads();
        s[threadIdx.x] += t;
        __syncthreads();
    }
    if (threadIdx.x < SCAN_B) part[threadIdx.x] = s[threadIdx.x] - v;
    if (threadIdx.x == 255) off[NN] = s[255];
}

__global__ __launch_bounds__(256) void k_scan3(int* __restrict__ off,
                                               const int* __restrict__ part,
                                               int* __restrict__ cur) {
    int i = blockIdx.x * 256 + threadIdx.x;
    if (i < NN) {
        int v = off[i] + part[blockIdx.x];
        off[i] = v;
        cur[i] = v;
    }
}

__global__ void k_scatter(const int* __restrict__ ei, int* __restrict__ cur,
                          int* __restrict__ ssrc) {
    int e = blockIdx.x * blockDim.x + threadIdx.x;
    if (e < NE) {
        int s = ei[e];
        int d = ei[NE + e];
        int pos = atomicAdd(&cur[d], 1);
        ssrc[pos] = s;
    }
}

// ---------------- one-shot weight prep ----------------
// blocks 0..767 : (g = b>>8, c = b&255) -> column c of fused layer-g weight (fp16)
// block 768     : Wc0 (fp32, 7 x 256) for layer 0
// block 769     : head fuse Wf = W2_3 @ Wo, bfh = b2_3 @ Wo (fp32)

__global__ __launch_bounds__(128) void k_prep(const float* __restrict__ W1_0,
                                              const float* __restrict__ W2_0,
                                              const float* __restrict__ b2_0,
                                              const float* __restrict__ W1s,
                                              const float* __restrict__ b1s,
                                              const float* __restrict__ W2s,
                                              const float* __restrict__ b2s,
                                              const float* __restrict__ Wo,
                                              float* __restrict__ Wc0,
                                              _Float16* __restrict__ Wt_all,
                                              float* __restrict__ dvec_all,
                                              float* __restrict__ bcat_all,
                                              float* __restrict__ Wf,
                                              float* __restrict__ bfh) {
    int b = blockIdx.x;
    int t = threadIdx.x;
    if (b < 768) {
        int g = b >> 8, c = b & 255;
        const float* W1g = W1s + (size_t)g * 256 * 128;
        const float* b1g = b1s + (size_t)g * 128;
        const float* W2p = (g == 0) ? W2_0 : W2s + (size_t)(g - 1) * 128 * 128;
        const float* b2p = (g == 0) ? b2_0 : b2s + (size_t)(g - 1) * 128;
        __shared__ float wc[128];
        int m = t;
        float v;
        if (c < 128) v = W1g[m * 128 + c] - W1g[(m + 128) * 128 + c];
        else         v = W1g[(m + 128) * 128 + (c - 128)];
        wc[m] = v;
        __syncthreads();
        int k = t;
        float acc = 0.f;
        #pragma unroll 8
        for (int mm = 0; mm < 128; mm++) acc += W2p[k * 128 + mm] * wc[mm];
        Wt_all[(size_t)g * 32768 + c * 128 + k] = (_Float16)acc;
        if (t == 0) {
            float dacc = 0.f;
            for (int mm = 0; mm < 128; mm++) dacc += b2p[mm] * wc[mm];
            dvec_all[g * 256 + c] = dacc;
            bcat_all[g * 256 + c] = (c < 128) ? b1g[c] : 0.f;
        }
    } else if (b == 768) {
        for (int idx = t; idx < IN_DIM * 256; idx += 128) {
            int k = idx >> 8, c = idx & 255;
            float v;
            if (c < 128) v = W1_0[k * 128 + c] - W1_0[(k + IN_DIM) * 128 + c];
            else         v = W1_0[(k + IN_DIM) * 128 + (c - 128)];
            Wc0[idx] = v;
        }
    } else {
        const float* W2l = W2s + (size_t)2 * 128 * 128;
        const float* b2l = b2s + (size_t)2 * 128;
        int k = t;
        #pragma unroll
        for (int r = 0; r < 3; r++) {
            float acc = 0.f;
            for (int m = 0; m < 128; m++) acc += W2l[k * 128 + m] * Wo[m * 3 + r];
            Wf[k * 3 + r] = acc;
        }
        if (k < 3) {
            float acc = 0.f;
            for (int m = 0; m < 128; m++) acc += b2l[m] * Wo[m * 3 + k];
            bfh[k] = acc;
        }
    }
}

// ---------------- layer-0: AB[50K x 256] = x[50K x 7] @ Wc0 + b1cat (fp16 out) ----------------

__global__ __launch_bounds__(256) void k_l0(const float* __restrict__ x,
                                            const float* __restrict__ Wc,
                                            const float* __restrict__ b1,
                                            _Float16* __restrict__ AB) {
    int i = blockIdx.x;
    int c = threadIdx.x;
    __shared__ float xs[IN_DIM];
    if (threadIdx.x < IN_DIM) xs[threadIdx.x] = x[i * IN_DIM + threadIdx.x];
    __syncthreads();
    float acc = (c < 128) ? b1[c] : 0.f;
    #pragma unroll
    for (int k = 0; k < IN_DIM; k++) acc += xs[k] * Wc[k * 256 + c];
    AB[i * 256 + c] = (_Float16)acc;
}

// ---------------- fused MFMA GEMM: AB = T[M x 128] @ Wt^T + deg*dvec + bcat (fp16 in/out) ----------------

__global__ __launch_bounds__(256) void k_gemm_ab(const _Float16* __restrict__ Tin,
                                                 const _Float16* __restrict__ Wt,
                                                 const float* __restrict__ dvec,
                                                 const float* __restrict__ bcat,
                                                 const float* __restrict__ degv,
                                                 _Float16* __restrict__ ABout) {
    __shared__ short Tl[64 * 136];   // +8 pad -> conflict-free ds_read_b128
    __shared__ float degl[64];
    int t = threadIdx.x;
    int m0 = blockIdx.x * 64;
    const short* Ts = (const short*)Tin;
    const short* Ws = (const short*)Wt;

    #pragma unroll
    for (int it = 0; it < 4; it++) {
        int idx = t + it * 256;
        int row = idx >> 4, seg = idx & 15;
        int gr = m0 + row;
        short8 v = {0, 0, 0, 0, 0, 0, 0, 0};
        if (gr < NN) v = *(const short8*)&Ts[gr * 128 + seg * 8];
        *(short8*)&Tl[row * 136 + seg * 8] = v;
    }
    if (t < 64) degl[t] = (m0 + t < NN) ? degv[m0 + t] : 0.f;
    __syncthreads();

    int lane = t & 63;
    int wv = t >> 6;
    int l15 = lane & 15, quad = lane >> 4;

    half8 a[4][4];
    #pragma unroll
    for (int rt = 0; rt < 4; rt++)
        #pragma unroll
        for (int ks = 0; ks < 4; ks++) {
            short8 s8 = *(const short8*)&Tl[(rt * 16 + l15) * 136 + ks * 32 + quad * 8];
            a[rt][ks] = __builtin_bit_cast(half8, s8);
        }

    int c0 = wv * 64;
    #pragma unroll
    for (int ct = 0; ct < 4; ct++) {
        int ccol = c0 + ct * 16 + l15;
        half8 b[4];
        #pragma unroll
        for (int ks = 0; ks < 4; ks++) {
            short8 s8 = *(const short8*)&Ws[ccol * 128 + ks * 32 + quad * 8];
            b[ks] = __builtin_bit_cast(half8, s8);
        }
        float bc = bcat[ccol], dv = dvec[ccol];
        #pragma unroll
        for (int rt = 0; rt < 4; rt++) {
            f32x4 acc = {0.f, 0.f, 0.f, 0.f};
            #pragma unroll
            for (int ks = 0; ks < 4; ks++)
                acc = __builtin_amdgcn_mfma_f32_16x16x32_f16(a[rt][ks], b[ks], acc, 0, 0, 0);
            #pragma unroll
            for (int r = 0; r < 4; r++) {
                int row = rt * 16 + quad * 4 + r;
                int grow = m0 + row;
                if (grow < NN) {
                    float v = acc[r] + degl[row] * dv + bc;
                    ABout[(size_t)grow * 256 + ccol] = (_Float16)v;
                }
            }
        }
    }
}

// ---------------- aggregation (+ optional fused head) ----------------

__device__ __forceinline__ float tanh_fast(float x) {
    float ax = __builtin_fabsf(x);
    float e = __expf(2.f * ax);
    float inv = __builtin_amdgcn_rcpf(e + 1.f);
    float r = 1.f - 2.f * inv;
    return __builtin_copysignf(r, x);
}

__device__ __forceinline__ float2 h2_to_f2(uint u) {
    __half2 h = *reinterpret_cast<__half2*>(&u);
    return __half22float2(h);
}

template <bool HEAD>
__global__ __launch_bounds__(256) void k_agg(const _Float16* __restrict__ AB,
                                             const int* __restrict__ off,
                                             const int* __restrict__ ssrc,
                                             _Float16* __restrict__ T,
                                             const float* __restrict__ Wf,
                                             const float* __restrict__ bfh,
                                             const float* __restrict__ bo,
                                             const float* __restrict__ degv,
                                             float* __restrict__ out) {
    int t = threadIdx.x;
    int i = blockIdx.x * 4 + (t >> 6);   // one wave per node
    int c2 = t & 63;                     // channels 2*c2, 2*c2+1
    const uint* ABu = (const uint*)AB;   // per row: A=[0,64), B=[64,128)
    float2 af = h2_to_f2(ABu[i * 128 + c2]);
    float a0 = af.x, a1 = af.y;
    int s0 = off[i], s1 = off[i + 1];
    float acc0 = 0.f, acc1 = 0.f;
    // masked unroll-8: 8 independent gathers in flight; OOB slots clamp to the
    // last valid index (L1-hit duplicates) and skip the tanh.
    for (int s = s0; s < s1; s += 8) {
        uint bv[8];
        #pragma unroll
        for (int q = 0; q < 8; q++) {
            int ss = s + q;
            int sc = (ss < s1) ? ss : (s1 - 1);
            int j = ssrc[sc];
            bv[q] = ABu[j * 128 + 64 + c2];
        }
        #pragma unroll
        for (int q = 0; q < 8; q++) {
            if (s + q < s1) {
                float2 bf = h2_to_f2(bv[q]);
                acc0 += tanh_fast(a0 + bf.x);
                acc1 += tanh_fast(a1 + bf.y);
            }
        }
    }
    if (!HEAD) {
        __half2 p = __float22half2_rn(make_float2(acc0, acc1));
        ((__half2*)T)[i * 64 + c2] = p;
    } else {
        float p0 = acc0 * Wf[(2 * c2) * 3 + 0] + acc1 * Wf[(2 * c2 + 1) * 3 + 0];
        float p1 = acc0 * Wf[(2 * c2) * 3 + 1] + acc1 * Wf[(2 * c2 + 1) * 3 + 1];
        float p2 = acc0 * Wf[(2 * c2) * 3 + 2] + acc1 * Wf[(2 * c2 + 1) * 3 + 2];
        #pragma unroll
        for (int o = 32; o > 0; o >>= 1) {
            p0 += __shfl_down(p0, o);
            p1 += __shfl_down(p1, o);
            p2 += __shfl_down(p2, o);
        }
        if (c2 == 0) {
            float d = degv[i];
            out[i * 3 + 0] = p0 + d * bfh[0] + bo[0];
            out[i * 3 + 1] = p1 + d * bfh[1] + bo[1];
            out[i * 3 + 2] = p2 + d * bfh[2] + bo[2];
        }
    }
}

// ---------------- host ----------------

extern "C" void kernel_launch(void* const* d_in, const int* in_sizes, int n_in,
                              void* d_out, int out_size, void* d_ws, size_t ws_size,
                              hipStream_t stream) {
    const float* x    = (const float*)d_in[0];
    const int*   ei   = (const int*)d_in[1];
    const float* W1_0 = (const float*)d_in[2];
    const float* b1_0 = (const float*)d_in[3];
    const float* W2_0 = (const float*)d_in[4];
    const float* b2_0 = (const float*)d_in[5];
    const float* W1s  = (const float*)d_in[6];
    const float* b1s  = (const float*)d_in[7];
    const float* W2s  = (const float*)d_in[8];
    const float* b2s  = (const float*)d_in[9];
    const float* Wo   = (const float*)d_in[10];
    const float* bo   = (const float*)d_in[11];
    float* out = (float*)d_out;

    char* w = (char*)d_ws;
    _Float16* AB = (_Float16*)w;                          w += (size_t)NN * 256 * 2;   // 25.6 MB
    _Float16* T  = (_Float16*)w;                          w += (size_t)NN * 128 * 2;   // 12.8 MB
    float* Wc0  = (float*)w;                              w += IN_DIM * 256 * 4;
    _Float16* Wt_all = (_Float16*)w;                      w += 3 * 256 * 128 * 2;
    float* dvec = (float*)w;                              w += 3 * 256 * 4;
    float* bcat = (float*)w;                              w += 3 * 256 * 4;
    float* Wf   = (float*)w;                              w += 2048;
    float* bfh  = (float*)w;                              w += 256;
    float* degv = (float*)w;                              w += (size_t)NN * 4;
    int* deg    = (int*)w;                                w += (size_t)NN * 4;
    int* off    = (int*)w;                                w += (size_t)(NN + 4) * 4;
    int* cur    = (int*)w;                                w += (size_t)NN * 4;
    int* ssrc   = (int*)w;                                w += (size_t)NE * 4;
    int* part   = (int*)w;                                w += 1024;

    const int B256 = 256;
    int gN = (NN + B256 - 1) / B256;
    int gE = (NE + B256 - 1) / B256;
    int gGemm = (NN + 63) / 64;   // 782
    int gAgg = NN / 4;            // 12500

    // ---- CSR by dst ----
    k_zero_int<<<gN, B256, 0, stream>>>(deg, NN);
    k_count<<<gE, B256, 0, stream>>>(ei, deg);
    k_scan1<<<SCAN_B, B256, 0, stream>>>(deg, off, part, degv);
    k_scan2<<<1, B256, 0, stream>>>(part, off);
    k_scan3<<<SCAN_B, B256, 0, stream>>>(off, part, cur);
    k_scatter<<<gE, B256, 0, stream>>>(ei, cur, ssrc);

    // ---- all weight prep in one launch ----
    k_prep<<<770, 128, 0, stream>>>(W1_0, W2_0, b2_0, W1s, b1s, W2s, b2s, Wo,
                                    Wc0, Wt_all, dvec, bcat, Wf, bfh);

    // ---- layer 0 ----
    k_l0<<<NN, 256, 0, stream>>>(x, Wc0, b1_0, AB);
    k_agg<false><<<gAgg, B256, 0, stream>>>(AB, off, ssrc, T, Wf, bfh, bo, degv, out);

    // ---- fused layers g = 0..2: AB = T @ Wt_g + deg*dvec_g + bcat_g ----
    for (int g = 0; g < 3; g++) {
        k_gemm_ab<<<gGemm, B256, 0, stream>>>(T, Wt_all + (size_t)g * 32768,
                                              dvec + g * 256, bcat + g * 256, degv, AB);
        if (g < 2)
            k_agg<false><<<gAgg, B256, 0, stream>>>(AB, off, ssrc, T, Wf, bfh, bo, degv, out);
        else
            k_agg<true><<<gAgg, B256, 0, stream>>>(AB, off, ssrc, T, Wf, bfh, bo, degv, out);
    }
}

// Round 6
// 412.796 us; speedup vs baseline: 2.4212x; 1.0639x over previous
//
#include <hip/hip_runtime.h>
#include <hip/hip_fp16.h>
#include <math.h>

#define NN 50000
#define NE 600000
#define IN_DIM 7
#define SCAN_B ((NN + 255) / 256)   // 196 blocks

typedef _Float16 half8 __attribute__((ext_vector_type(8)));
typedef short short8 __attribute__((ext_vector_type(8)));
typedef float f32x4  __attribute__((ext_vector_type(4)));
typedef unsigned int uint;

// ---------------- CSR build ----------------

__global__ void k_zero_int(int* __restrict__ p, int n) {
    int i = blockIdx.x * blockDim.x + threadIdx.x;
    if (i < n) p[i] = 0;
}

__global__ void k_count(const int* __restrict__ ei, int* __restrict__ deg) {
    int e = blockIdx.x * blockDim.x + threadIdx.x;
    if (e < NE) atomicAdd(&deg[ei[NE + e]], 1);
}

__global__ __launch_bounds__(256) void k_scan1(const int* __restrict__ deg,
                                               int* __restrict__ off,
                                               int* __restrict__ part,
                                               float* __restrict__ degv) {
    __shared__ int s[256];
    int i = blockIdx.x * 256 + threadIdx.x;
    int v = (i < NN) ? deg[i] : 0;
    s[threadIdx.x] = v;
    __syncthreads();
    #pragma unroll
    for (int o = 1; o < 256; o <<= 1) {
        int t = (threadIdx.x >= o) ? s[threadIdx.x - o] : 0;
        __syncthreads();
        s[threadIdx.x] += t;
        __syncthreads();
    }
    if (i < NN) { off[i] = s[threadIdx.x] - v; degv[i] = (float)v; }
    if (threadIdx.x == 255) part[blockIdx.x] = s[255];
}

__global__ __launch_bounds__(256) void k_scan2(int* __restrict__ part,
                                               int* __restrict__ off) {
    __shared__ int s[256];
    int v = (threadIdx.x < SCAN_B) ? part[threadIdx.x] : 0;
    s[threadIdx.x] = v;
    __syncthreads();
    #pragma unroll
    for (int o = 1; o < 256; o <<= 1) {
        int t = (threadIdx.x >= o) ? s[threadIdx.x - o] : 0;
        __syncthreads();
        s[threadIdx.x] += t;
        __syncthreads();
    }
    if (threadIdx.x < SCAN_B) part[threadIdx.x] = s[threadIdx.x] - v;
    if (threadIdx.x == 255) off[NN] = s[255];
}

__global__ __launch_bounds__(256) void k_scan3(int* __restrict__ off,
                                               const int* __restrict__ part,
                                               int* __restrict__ cur) {
    int i = blockIdx.x * 256 + threadIdx.x;
    if (i < NN) {
        int v = off[i] + part[blockIdx.x];
        off[i] = v;
        cur[i] = v;
    }
}

__global__ void k_scatter(const int* __restrict__ ei, int* __restrict__ cur,
                          int* __restrict__ ssrc) {
    int e = blockIdx.x * blockDim.x + threadIdx.x;
    if (e < NE) {
        int s = ei[e];
        int d = ei[NE + e];
        int pos = atomicAdd(&cur[d], 1);
        ssrc[pos] = s;
    }
}

// ---------------- one-shot weight prep ----------------

__global__ __launch_bounds__(128) void k_prep(const float* __restrict__ W1_0,
                                              const float* __restrict__ W2_0,
                                              const float* __restrict__ b2_0,
                                              const float* __restrict__ W1s,
                                              const float* __restrict__ b1s,
                                              const float* __restrict__ W2s,
                                              const float* __restrict__ b2s,
                                              const float* __restrict__ Wo,
                                              float* __restrict__ Wc0,
                                              _Float16* __restrict__ Wt_all,
                                              float* __restrict__ dvec_all,
                                              float* __restrict__ bcat_all,
                                              float* __restrict__ Wf,
                                              float* __restrict__ bfh) {
    int b = blockIdx.x;
    int t = threadIdx.x;
    if (b < 768) {
        int g = b >> 8, c = b & 255;
        const float* W1g = W1s + (size_t)g * 256 * 128;
        const float* b1g = b1s + (size_t)g * 128;
        const float* W2p = (g == 0) ? W2_0 : W2s + (size_t)(g - 1) * 128 * 128;
        const float* b2p = (g == 0) ? b2_0 : b2s + (size_t)(g - 1) * 128;
        __shared__ float wc[128];
        int m = t;
        float v;
        if (c < 128) v = W1g[m * 128 + c] - W1g[(m + 128) * 128 + c];
        else         v = W1g[(m + 128) * 128 + (c - 128)];
        wc[m] = v;
        __syncthreads();
        int k = t;
        float acc = 0.f;
        #pragma unroll 8
        for (int mm = 0; mm < 128; mm++) acc += W2p[k * 128 + mm] * wc[mm];
        Wt_all[(size_t)g * 32768 + c * 128 + k] = (_Float16)acc;
        if (t == 0) {
            float dacc = 0.f;
            for (int mm = 0; mm < 128; mm++) dacc += b2p[mm] * wc[mm];
            dvec_all[g * 256 + c] = dacc;
            bcat_all[g * 256 + c] = (c < 128) ? b1g[c] : 0.f;
        }
    } else if (b == 768) {
        for (int idx = t; idx < IN_DIM * 256; idx += 128) {
            int k = idx >> 8, c = idx & 255;
            float v;
            if (c < 128) v = W1_0[k * 128 + c] - W1_0[(k + IN_DIM) * 128 + c];
            else         v = W1_0[(k + IN_DIM) * 128 + (c - 128)];
            Wc0[idx] = v;
        }
    } else {
        const float* W2l = W2s + (size_t)2 * 128 * 128;
        const float* b2l = b2s + (size_t)2 * 128;
        int k = t;
        #pragma unroll
        for (int r = 0; r < 3; r++) {
            float acc = 0.f;
            for (int m = 0; m < 128; m++) acc += W2l[k * 128 + m] * Wo[m * 3 + r];
            Wf[k * 3 + r] = acc;
        }
        if (k < 3) {
            float acc = 0.f;
            for (int m = 0; m < 128; m++) acc += b2l[m] * Wo[m * 3 + k];
            bfh[k] = acc;
        }
    }
}

// ---------------- layer-0: AB[50K x 256] = x[50K x 7] @ Wc0 + b1cat (fp16 out) ----------------

__global__ __launch_bounds__(256) void k_l0(const float* __restrict__ x,
                                            const float* __restrict__ Wc,
                                            const float* __restrict__ b1,
                                            _Float16* __restrict__ AB) {
    int i = blockIdx.x;
    int c = threadIdx.x;
    __shared__ float xs[IN_DIM];
    if (threadIdx.x < IN_DIM) xs[threadIdx.x] = x[i * IN_DIM + threadIdx.x];
    __syncthreads();
    float acc = (c < 128) ? b1[c] : 0.f;
    #pragma unroll
    for (int k = 0; k < IN_DIM; k++) acc += xs[k] * Wc[k * 256 + c];
    AB[i * 256 + c] = (_Float16)acc;
}

// ---------------- fused MFMA GEMM: AB = T[M x 128] @ Wt^T + deg*dvec + bcat (fp16 in/out) ----------------

__global__ __launch_bounds__(256) void k_gemm_ab(const _Float16* __restrict__ Tin,
                                                 const _Float16* __restrict__ Wt,
                                                 const float* __restrict__ dvec,
                                                 const float* __restrict__ bcat,
                                                 const float* __restrict__ degv,
                                                 _Float16* __restrict__ ABout) {
    __shared__ short Tl[64 * 136];   // +8 pad -> conflict-free ds_read_b128
    __shared__ float degl[64];
    int t = threadIdx.x;
    int m0 = blockIdx.x * 64;
    const short* Ts = (const short*)Tin;
    const short* Ws = (const short*)Wt;

    #pragma unroll
    for (int it = 0; it < 4; it++) {
        int idx = t + it * 256;
        int row = idx >> 4, seg = idx & 15;
        int gr = m0 + row;
        short8 v = {0, 0, 0, 0, 0, 0, 0, 0};
        if (gr < NN) v = *(const short8*)&Ts[gr * 128 + seg * 8];
        *(short8*)&Tl[row * 136 + seg * 8] = v;
    }
    if (t < 64) degl[t] = (m0 + t < NN) ? degv[m0 + t] : 0.f;
    __syncthreads();

    int lane = t & 63;
    int wv = t >> 6;
    int l15 = lane & 15, quad = lane >> 4;

    half8 a[4][4];
    #pragma unroll
    for (int rt = 0; rt < 4; rt++)
        #pragma unroll
        for (int ks = 0; ks < 4; ks++) {
            short8 s8 = *(const short8*)&Tl[(rt * 16 + l15) * 136 + ks * 32 + quad * 8];
            a[rt][ks] = __builtin_bit_cast(half8, s8);
        }

    int c0 = wv * 64;
    #pragma unroll
    for (int ct = 0; ct < 4; ct++) {
        int ccol = c0 + ct * 16 + l15;
        half8 b[4];
        #pragma unroll
        for (int ks = 0; ks < 4; ks++) {
            short8 s8 = *(const short8*)&Ws[ccol * 128 + ks * 32 + quad * 8];
            b[ks] = __builtin_bit_cast(half8, s8);
        }
        float bc = bcat[ccol], dv = dvec[ccol];
        #pragma unroll
        for (int rt = 0; rt < 4; rt++) {
            f32x4 acc = {0.f, 0.f, 0.f, 0.f};
            #pragma unroll
            for (int ks = 0; ks < 4; ks++)
                acc = __builtin_amdgcn_mfma_f32_16x16x32_f16(a[rt][ks], b[ks], acc, 0, 0, 0);
            #pragma unroll
            for (int r = 0; r < 4; r++) {
                int row = rt * 16 + quad * 4 + r;
                int grow = m0 + row;
                if (grow < NN) {
                    float v = acc[r] + degl[row] * dv + bc;
                    ABout[(size_t)grow * 256 + ccol] = (_Float16)v;
                }
            }
        }
    }
}

// ---------------- aggregation (+ optional fused head) ----------------
// One wave per node; lanes 0-31 take even edges, 32-63 odd edges; each lane
// covers 4 channels (one uint2 = 4 fp16 per gather). Cross-iteration prefetch
// keeps 8 dwordx2 in flight. Final cross-half combine: shfl_down(32).

__device__ __forceinline__ float tanh_fast(float x) {
    float ax = __builtin_fabsf(x);
    float e = __expf(2.f * ax);
    float inv = __builtin_amdgcn_rcpf(e + 1.f);
    float r = 1.f - 2.f * inv;
    return __builtin_copysignf(r, x);
}

__device__ __forceinline__ float2 h2_to_f2(uint u) {
    __half2 h = *reinterpret_cast<__half2*>(&u);
    return __half22float2(h);
}

template <bool HEAD>
__global__ __launch_bounds__(256) void k_agg(const _Float16* __restrict__ AB,
                                             const int* __restrict__ off,
                                             const int* __restrict__ ssrc,
                                             _Float16* __restrict__ T,
                                             const float* __restrict__ Wf,
                                             const float* __restrict__ bfh,
                                             const float* __restrict__ bo,
                                             const float* __restrict__ degv,
                                             float* __restrict__ out) {
    int t = threadIdx.x;
    int i = blockIdx.x * 4 + (t >> 6);   // one wave per node
    int lane = t & 63;
    int q = lane & 31;                   // channel quad: channels 4q..4q+3
    int eoff = lane >> 5;                // 0: even edges, 1: odd edges
    const uint2* AB2 = (const uint2*)AB; // per row: 64 uint2, A=[0,32), B=[32,64)

    uint2 av = AB2[(size_t)i * 64 + q];
    float2 a01 = h2_to_f2(av.x), a23 = h2_to_f2(av.y);
    int s0 = off[i], s1 = off[i + 1];
    float acc0 = 0.f, acc1 = 0.f, acc2 = 0.f, acc3 = 0.f;

    uint2 bv[4];
    #define LOAD_BATCH(SB)                                        \
        _Pragma("unroll")                                         \
        for (int k2 = 0; k2 < 4; k2++) {                          \
            int ss = (SB) + 2 * k2 + eoff;                        \
            int sc = (ss < s1) ? ss : (s1 - 1);                   \
            int j = ssrc[sc];                                     \
            bv[k2] = AB2[(size_t)j * 64 + 32 + q];                \
        }

    if (s0 < s1) { LOAD_BATCH(s0); }
    for (int s = s0; s < s1; s += 8) {
        uint2 cur[4];
        #pragma unroll
        for (int k2 = 0; k2 < 4; k2++) cur[k2] = bv[k2];
        if (s + 8 < s1) { LOAD_BATCH(s + 8); }
        #pragma unroll
        for (int k2 = 0; k2 < 4; k2++) {
            int ss = s + 2 * k2 + eoff;
            if (ss < s1) {
                float2 b01 = h2_to_f2(cur[k2].x), b23 = h2_to_f2(cur[k2].y);
                acc0 += tanh_fast(a01.x + b01.x);
                acc1 += tanh_fast(a01.y + b01.y);
                acc2 += tanh_fast(a23.x + b23.x);
                acc3 += tanh_fast(a23.y + b23.y);
            }
        }
    }
    #undef LOAD_BATCH

    if (!HEAD) {
        // combine edge-halves, lanes 0-31 write 4 channels (uint2)
        acc0 += __shfl_down(acc0, 32);
        acc1 += __shfl_down(acc1, 32);
        acc2 += __shfl_down(acc2, 32);
        acc3 += __shfl_down(acc3, 32);
        if (lane < 32) {
            __half2 p01 = __float22half2_rn(make_float2(acc0, acc1));
            __half2 p23 = __float22half2_rn(make_float2(acc2, acc3));
            uint2 pv;
            pv.x = *reinterpret_cast<uint*>(&p01);
            pv.y = *reinterpret_cast<uint*>(&p23);
            ((uint2*)T)[(size_t)i * 32 + q] = pv;
        }
    } else {
        // every lane projects its 4 channels; full-wave reduce sums both
        // edge-halves and all channels at once.
        int ch = 4 * q;
        float p0 = acc0 * Wf[ch * 3 + 0] + acc1 * Wf[(ch + 1) * 3 + 0]
                 + acc2 * Wf[(ch + 2) * 3 + 0] + acc3 * Wf[(ch + 3) * 3 + 0];
        float p1 = acc0 * Wf[ch * 3 + 1] + acc1 * Wf[(ch + 1) * 3 + 1]
                 + acc2 * Wf[(ch + 2) * 3 + 1] + acc3 * Wf[(ch + 3) * 3 + 1];
        float p2 = acc0 * Wf[ch * 3 + 2] + acc1 * Wf[(ch + 1) * 3 + 2]
                 + acc2 * Wf[(ch + 2) * 3 + 2] + acc3 * Wf[(ch + 3) * 3 + 2];
        #pragma unroll
        for (int o = 32; o > 0; o >>= 1) {
            p0 += __shfl_down(p0, o);
            p1 += __shfl_down(p1, o);
            p2 += __shfl_down(p2, o);
        }
        if (lane == 0) {
            float d = degv[i];
            out[i * 3 + 0] = p0 + d * bfh[0] + bo[0];
            out[i * 3 + 1] = p1 + d * bfh[1] + bo[1];
            out[i * 3 + 2] = p2 + d * bfh[2] + bo[2];
        }
    }
}

// ---------------- host ----------------

extern "C" void kernel_launch(void* const* d_in, const int* in_sizes, int n_in,
                              void* d_out, int out_size, void* d_ws, size_t ws_size,
                              hipStream_t stream) {
    const float* x    = (const float*)d_in[0];
    const int*   ei   = (const int*)d_in[1];
    const float* W1_0 = (const float*)d_in[2];
    const float* b1_0 = (const float*)d_in[3];
    const float* W2_0 = (const float*)d_in[4];
    const float* b2_0 = (const float*)d_in[5];
    const float* W1s  = (const float*)d_in[6];
    const float* b1s  = (const float*)d_in[7];
    const float* W2s  = (const float*)d_in[8];
    const float* b2s  = (const float*)d_in[9];
    const float* Wo   = (const float*)d_in[10];
    const float* bo   = (const float*)d_in[11];
    float* out = (float*)d_out;

    char* w = (char*)d_ws;
    _Float16* AB = (_Float16*)w;                          w += (size_t)NN * 256 * 2;   // 25.6 MB
    _Float16* T  = (_Float16*)w;                          w += (size_t)NN * 128 * 2;   // 12.8 MB
    float* Wc0  = (float*)w;                              w += IN_DIM * 256 * 4;
    _Float16* Wt_all = (_Float16*)w;                      w += 3 * 256 * 128 * 2;
    float* dvec = (float*)w;                              w += 3 * 256 * 4;
    float* bcat = (float*)w;                              w += 3 * 256 * 4;
    float* Wf   = (float*)w;                              w += 2048;
    float* bfh  = (float*)w;                              w += 256;
    float* degv = (float*)w;                              w += (size_t)NN * 4;
    int* deg    = (int*)w;                                w += (size_t)NN * 4;
    int* off    = (int*)w;                                w += (size_t)(NN + 4) * 4;
    int* cur    = (int*)w;                                w += (size_t)NN * 4;
    int* ssrc   = (int*)w;                                w += (size_t)NE * 4;
    int* part   = (int*)w;                                w += 1024;

    const int B256 = 256;
    int gN = (NN + B256 - 1) / B256;
    int gE = (NE + B256 - 1) / B256;
    int gGemm = (NN + 63) / 64;   // 782
    int gAgg = NN / 4;            // 12500

    // ---- CSR by dst ----
    k_zero_int<<<gN, B256, 0, stream>>>(deg, NN);
    k_count<<<gE, B256, 0, stream>>>(ei, deg);
    k_scan1<<<SCAN_B, B256, 0, stream>>>(deg, off, part, degv);
    k_scan2<<<1, B256, 0, stream>>>(part, off);
    k_scan3<<<SCAN_B, B256, 0, stream>>>(off, part, cur);
    k_scatter<<<gE, B256, 0, stream>>>(ei, cur, ssrc);

    // ---- all weight prep in one launch ----
    k_prep<<<770, 128, 0, stream>>>(W1_0, W2_0, b2_0, W1s, b1s, W2s, b2s, Wo,
                                    Wc0, Wt_all, dvec, bcat, Wf, bfh);

    // ---- layer 0 ----
    k_l0<<<NN, 256, 0, stream>>>(x, Wc0, b1_0, AB);
    k_agg<false><<<gAgg, B256, 0, stream>>>(AB, off, ssrc, T, Wf, bfh, bo, degv, out);

    // ---- fused layers g = 0..2: AB = T @ Wt_g + deg*dvec_g + bcat_g ----
    for (int g = 0; g < 3; g++) {
        k_gemm_ab<<<gGemm, B256, 0, stream>>>(T, Wt_all + (size_t)g * 32768,
                                              dvec + g * 256, bcat + g * 256, degv, AB);
        if (g < 2)
            k_agg<false><<<gAgg, B256, 0, stream>>>(AB, off, ssrc, T, Wf, bfh, bo, degv, out);
        else
            k_agg<true><<<gAgg, B256, 0, stream>>>(AB, off, ssrc, T, Wf, bfh, bo, degv, out);
    }
}

// Round 7
// 410.761 us; speedup vs baseline: 2.4332x; 1.0050x over previous
//
#include <hip/hip_runtime.h>
#include <hip/hip_fp16.h>
#include <math.h>

#define NN 50000
#define NE 600000
#define IN_DIM 7
#define SCAN_B ((NN + 255) / 256)   // 196 blocks

// agg stores AB pre-scaled by -2*log2(e) so tanh(a+b) = 2*rcp(1+exp2(a'+b')) - 1
#define NEG2LOG2E -2.8853900817779268f

typedef _Float16 half8 __attribute__((ext_vector_type(8)));
typedef short short8 __attribute__((ext_vector_type(8)));
typedef float f32x4  __attribute__((ext_vector_type(4)));
typedef unsigned int uint;

#if __has_builtin(__builtin_amdgcn_exp2f)
#define EXP2F(x) __builtin_amdgcn_exp2f(x)
#else
#define EXP2F(x) __expf(0.6931471805599453f * (x))
#endif

// ---------------- CSR build ----------------

__global__ void k_zero_int(int* __restrict__ p, int n) {
    int i = blockIdx.x * blockDim.x + threadIdx.x;
    if (i < n) p[i] = 0;
}

__global__ void k_count(const int* __restrict__ ei, int* __restrict__ deg) {
    int e = blockIdx.x * blockDim.x + threadIdx.x;
    if (e < NE) atomicAdd(&deg[ei[NE + e]], 1);
}

__global__ __launch_bounds__(256) void k_scan1(const int* __restrict__ deg,
                                               int* __restrict__ off,
                                               int* __restrict__ part,
                                               float* __restrict__ degv) {
    __shared__ int s[256];
    int i = blockIdx.x * 256 + threadIdx.x;
    int v = (i < NN) ? deg[i] : 0;
    s[threadIdx.x] = v;
    __syncthreads();
    #pragma unroll
    for (int o = 1; o < 256; o <<= 1) {
        int t = (threadIdx.x >= o) ? s[threadIdx.x - o] : 0;
        __syncthreads();
        s[threadIdx.x] += t;
        __syncthreads();
    }
    if (i < NN) { off[i] = s[threadIdx.x] - v; degv[i] = (float)v; }
    if (threadIdx.x == 255) part[blockIdx.x] = s[255];
}

__global__ __launch_bounds__(256) void k_scan2(int* __restrict__ part,
                                               int* __restrict__ off) {
    __shared__ int s[256];
    int v = (threadIdx.x < SCAN_B) ? part[threadIdx.x] : 0;
    s[threadIdx.x] = v;
    __syncthreads();
    #pragma unroll
    for (int o = 1; o < 256; o <<= 1) {
        int t = (threadIdx.x >= o) ? s[threadIdx.x - o] : 0;
        __syncthreads();
        s[threadIdx.x] += t;
        __syncthreads();
    }
    if (threadIdx.x < SCAN_B) part[threadIdx.x] = s[threadIdx.x] - v;
    if (threadIdx.x == 255) off[NN] = s[255];
}

__global__ __launch_bounds__(256) void k_scan3(int* __restrict__ off,
                                               const int* __restrict__ part,
                                               int* __restrict__ cur) {
    int i = blockIdx.x * 256 + threadIdx.x;
    if (i < NN) {
        int v = off[i] + part[blockIdx.x];
        off[i] = v;
        cur[i] = v;
    }
}

__global__ void k_scatter(const int* __restrict__ ei, int* __restrict__ cur,
                          int* __restrict__ ssrc) {
    int e = blockIdx.x * blockDim.x + threadIdx.x;
    if (e < NE) {
        int s = ei[e];
        int d = ei[NE + e];
        int pos = atomicAdd(&cur[d], 1);
        ssrc[pos] = s;
    }
}

// ---------------- one-shot weight prep ----------------
// bfh2[r] = (b2_3 @ Wo)[r] - sum_k Wf[k][r]   (folds the "-deg" of Sum tanh = 2*Sum r - deg)

__global__ __launch_bounds__(128) void k_prep(const float* __restrict__ W1_0,
                                              const float* __restrict__ W2_0,
                                              const float* __restrict__ b2_0,
                                              const float* __restrict__ W1s,
                                              const float* __restrict__ b1s,
                                              const float* __restrict__ W2s,
                                              const float* __restrict__ b2s,
                                              const float* __restrict__ Wo,
                                              float* __restrict__ Wc0,
                                              _Float16* __restrict__ Wt_all,
                                              float* __restrict__ dvec_all,
                                              float* __restrict__ bcat_all,
                                              float* __restrict__ Wf,
                                              float* __restrict__ bfh2) {
    int b = blockIdx.x;
    int t = threadIdx.x;
    if (b < 768) {
        int g = b >> 8, c = b & 255;
        const float* W1g = W1s + (size_t)g * 256 * 128;
        const float* b1g = b1s + (size_t)g * 128;
        const float* W2p = (g == 0) ? W2_0 : W2s + (size_t)(g - 1) * 128 * 128;
        const float* b2p = (g == 0) ? b2_0 : b2s + (size_t)(g - 1) * 128;
        __shared__ float wc[128];
        int m = t;
        float v;
        if (c < 128) v = W1g[m * 128 + c] - W1g[(m + 128) * 128 + c];
        else         v = W1g[(m + 128) * 128 + (c - 128)];
        wc[m] = v;
        __syncthreads();
        int k = t;
        float acc = 0.f;
        #pragma unroll 8
        for (int mm = 0; mm < 128; mm++) acc += W2p[k * 128 + mm] * wc[mm];
        Wt_all[(size_t)g * 32768 + c * 128 + k] = (_Float16)acc;
        if (t == 0) {
            float dacc = 0.f;
            for (int mm = 0; mm < 128; mm++) dacc += b2p[mm] * wc[mm];
            dvec_all[g * 256 + c] = dacc;
            bcat_all[g * 256 + c] = (c < 128) ? b1g[c] : 0.f;
        }
    } else if (b == 768) {
        for (int idx = t; idx < IN_DIM * 256; idx += 128) {
            int k = idx >> 8, c = idx & 255;
            float v;
            if (c < 128) v = W1_0[k * 128 + c] - W1_0[(k + IN_DIM) * 128 + c];
            else         v = W1_0[(k + IN_DIM) * 128 + (c - 128)];
            Wc0[idx] = v;
        }
    } else {
        const float* W2l = W2s + (size_t)2 * 128 * 128;
        const float* b2l = b2s + (size_t)2 * 128;
        int k = t;
        #pragma unroll
        for (int r = 0; r < 3; r++) {
            float acc = 0.f;
            for (int m = 0; m < 128; m++) acc += W2l[k * 128 + m] * Wo[m * 3 + r];
            Wf[k * 3 + r] = acc;
        }
        __syncthreads();
        if (k < 3) {
            float acc = 0.f;
            for (int m = 0; m < 128; m++) acc += b2l[m] * Wo[m * 3 + k];
            float wfsum = 0.f;
            for (int m = 0; m < 128; m++) wfsum += Wf[m * 3 + k];
            bfh2[k] = acc - wfsum;
        }
    }
}

// ---------------- layer-0: AB = (-2log2e)*(x @ Wc0 + b1cat) (fp16 out) ----------------

__global__ __launch_bounds__(256) void k_l0(const float* __restrict__ x,
                                            const float* __restrict__ Wc,
                                            const float* __restrict__ b1,
                                            _Float16* __restrict__ AB) {
    int i = blockIdx.x;
    int c = threadIdx.x;
    __shared__ float xs[IN_DIM];
    if (threadIdx.x < IN_DIM) xs[threadIdx.x] = x[i * IN_DIM + threadIdx.x];
    __syncthreads();
    float acc = (c < 128) ? b1[c] : 0.f;
    #pragma unroll
    for (int k = 0; k < IN_DIM; k++) acc += xs[k] * Wc[k * 256 + c];
    AB[i * 256 + c] = (_Float16)(NEG2LOG2E * acc);
}

// ---------------- fused MFMA GEMM: AB = (-2log2e)*(T @ Wt^T + deg*dvec + bcat) ----------------

__global__ __launch_bounds__(256) void k_gemm_ab(const _Float16* __restrict__ Tin,
                                                 const _Float16* __restrict__ Wt,
                                                 const float* __restrict__ dvec,
                                                 const float* __restrict__ bcat,
                                                 const float* __restrict__ degv,
                                                 _Float16* __restrict__ ABout) {
    __shared__ short Tl[64 * 136];   // +8 pad -> conflict-free ds_read_b128
    __shared__ float degl[64];
    int t = threadIdx.x;
    int m0 = blockIdx.x * 64;
    const short* Ts = (const short*)Tin;
    const short* Ws = (const short*)Wt;

    #pragma unroll
    for (int it = 0; it < 4; it++) {
        int idx = t + it * 256;
        int row = idx >> 4, seg = idx & 15;
        int gr = m0 + row;
        short8 v = {0, 0, 0, 0, 0, 0, 0, 0};
        if (gr < NN) v = *(const short8*)&Ts[gr * 128 + seg * 8];
        *(short8*)&Tl[row * 136 + seg * 8] = v;
    }
    if (t < 64) degl[t] = (m0 + t < NN) ? degv[m0 + t] : 0.f;
    __syncthreads();

    int lane = t & 63;
    int wv = t >> 6;
    int l15 = lane & 15, quad = lane >> 4;

    half8 a[4][4];
    #pragma unroll
    for (int rt = 0; rt < 4; rt++)
        #pragma unroll
        for (int ks = 0; ks < 4; ks++) {
            short8 s8 = *(const short8*)&Tl[(rt * 16 + l15) * 136 + ks * 32 + quad * 8];
            a[rt][ks] = __builtin_bit_cast(half8, s8);
        }

    int c0 = wv * 64;
    #pragma unroll
    for (int ct = 0; ct < 4; ct++) {
        int ccol = c0 + ct * 16 + l15;
        half8 b[4];
        #pragma unroll
        for (int ks = 0; ks < 4; ks++) {
            short8 s8 = *(const short8*)&Ws[ccol * 128 + ks * 32 + quad * 8];
            b[ks] = __builtin_bit_cast(half8, s8);
        }
        float bc = bcat[ccol], dv = dvec[ccol];
        #pragma unroll
        for (int rt = 0; rt < 4; rt++) {
            f32x4 acc = {0.f, 0.f, 0.f, 0.f};
            #pragma unroll
            for (int ks = 0; ks < 4; ks++)
                acc = __builtin_amdgcn_mfma_f32_16x16x32_f16(a[rt][ks], b[ks], acc, 0, 0, 0);
            #pragma unroll
            for (int r = 0; r < 4; r++) {
                int row = rt * 16 + quad * 4 + r;
                int grow = m0 + row;
                if (grow < NN) {
                    float v = acc[r] + degl[row] * dv + bc;
                    ABout[(size_t)grow * 256 + ccol] = (_Float16)(NEG2LOG2E * v);
                }
            }
        }
    }
}

// ---------------- aggregation (+ optional fused head) ----------------
// One wave per node. 16 lanes per edge (8 channels each, uint4 = 8 fp16),
// 4 edge-groups per wave. AB is pre-scaled: tanh(a+b) = 2*rcp(1+exp2(a'+b')) - 1.
// Loop accumulates r = rcp(1+exp2(u)); Sum tanh = 2*Sum r - deg (deg applied at epilogue).

template <bool HEAD>
__global__ __launch_bounds__(256) void k_agg(const _Float16* __restrict__ AB,
                                             const int* __restrict__ off,
                                             const int* __restrict__ ssrc,
                                             _Float16* __restrict__ T,
                                             const float* __restrict__ Wf,
                                             const float* __restrict__ bfh2,
                                             const float* __restrict__ bo,
                                             float* __restrict__ out) {
    int t = threadIdx.x;
    int i = blockIdx.x * 4 + (t >> 6);   // one wave per node
    int lane = t & 63;
    int q = lane & 15;                   // channel octet: channels 8q..8q+7
    int g = lane >> 4;                   // edge group 0..3
    const uint4* AB4 = (const uint4*)AB; // 32 uint4 per row: A=[0,16), B=[16,32)

    uint4 av = AB4[(size_t)i * 32 + q];
    uint ah[4] = {av.x, av.y, av.z, av.w};
    int s0 = off[i], s1 = off[i + 1];
    float acc[8];
    #pragma unroll
    for (int k = 0; k < 8; k++) acc[k] = 0.f;

    uint4 bv;
    #define LOAD_BATCH(SB)                                        \
        {                                                         \
            int ss = (SB) + g;                                    \
            int sc = (ss < s1) ? ss : (s1 - 1);                   \
            int j = ssrc[sc];                                     \
            bv = AB4[(size_t)j * 32 + 16 + q];                    \
        }

    if (s0 < s1) { LOAD_BATCH(s0); }
    for (int s = s0; s < s1; s += 4) {
        uint4 cv = bv;
        if (s + 4 < s1) { LOAD_BATCH(s + 4); }
        if (s + g < s1) {
            uint bh[4] = {cv.x, cv.y, cv.z, cv.w};
            #pragma unroll
            for (int k = 0; k < 4; k++) {
                __half2 ua = *reinterpret_cast<__half2*>(&ah[k]);
                __half2 ub = *reinterpret_cast<__half2*>(&bh[k]);
                __half2 u2 = __hadd2(ua, ub);
                float2 uf = __half22float2(u2);
                float e0 = EXP2F(uf.x);
                float e1 = EXP2F(uf.y);
                acc[2 * k + 0] += __builtin_amdgcn_rcpf(1.f + e0);
                acc[2 * k + 1] += __builtin_amdgcn_rcpf(1.f + e1);
            }
        }
    }
    #undef LOAD_BATCH

    if (!HEAD) {
        // reduce the 4 edge-groups; lanes 0-15 write 8 channels (uint4)
        #pragma unroll
        for (int k = 0; k < 8; k++) {
            acc[k] += __shfl_xor(acc[k], 16);
            acc[k] += __shfl_xor(acc[k], 32);
        }
        if (lane < 16) {
            float degf = (float)(s1 - s0);
            uint4 pv;
            uint* pu = reinterpret_cast<uint*>(&pv);
            #pragma unroll
            for (int k = 0; k < 4; k++) {
                __half2 p = __float22half2_rn(make_float2(
                    2.f * acc[2 * k + 0] - degf, 2.f * acc[2 * k + 1] - degf));
                pu[k] = *reinterpret_cast<uint*>(&p);
            }
            ((uint4*)T)[(size_t)i * 16 + q] = pv;
        }
    } else {
        // each lane projects its 8 channels (partial over its edge group);
        // full-wave reduce sums groups AND channels. out = 2*P + deg*bfh2 + bo.
        int ch = 8 * q;
        float p0 = 0.f, p1 = 0.f, p2 = 0.f;
        #pragma unroll
        for (int k = 0; k < 8; k++) {
            float v = acc[k];
            p0 += v * Wf[(ch + k) * 3 + 0];
            p1 += v * Wf[(ch + k) * 3 + 1];
            p2 += v * Wf[(ch + k) * 3 + 2];
        }
        #pragma unroll
        for (int o = 32; o > 0; o >>= 1) {
            p0 += __shfl_down(p0, o);
            p1 += __shfl_down(p1, o);
            p2 += __shfl_down(p2, o);
        }
        if (lane == 0) {
            float degf = (float)(s1 - s0);
            out[i * 3 + 0] = 2.f * p0 + degf * bfh2[0] + bo[0];
            out[i * 3 + 1] = 2.f * p1 + degf * bfh2[1] + bo[1];
            out[i * 3 + 2] = 2.f * p2 + degf * bfh2[2] + bo[2];
        }
    }
}

// ---------------- host ----------------

extern "C" void kernel_launch(void* const* d_in, const int* in_sizes, int n_in,
                              void* d_out, int out_size, void* d_ws, size_t ws_size,
                              hipStream_t stream) {
    const float* x    = (const float*)d_in[0];
    const int*   ei   = (const int*)d_in[1];
    const float* W1_0 = (const float*)d_in[2];
    const float* b1_0 = (const float*)d_in[3];
    const float* W2_0 = (const float*)d_in[4];
    const float* b2_0 = (const float*)d_in[5];
    const float* W1s  = (const float*)d_in[6];
    const float* b1s  = (const float*)d_in[7];
    const float* W2s  = (const float*)d_in[8];
    const float* b2s  = (const float*)d_in[9];
    const float* Wo   = (const float*)d_in[10];
    const float* bo   = (const float*)d_in[11];
    float* out = (float*)d_out;

    char* w = (char*)d_ws;
    _Float16* AB = (_Float16*)w;                          w += (size_t)NN * 256 * 2;   // 25.6 MB
    _Float16* T  = (_Float16*)w;                          w += (size_t)NN * 128 * 2;   // 12.8 MB
    float* Wc0  = (float*)w;                              w += IN_DIM * 256 * 4;
    _Float16* Wt_all = (_Float16*)w;                      w += 3 * 256 * 128 * 2;
    float* dvec = (float*)w;                              w += 3 * 256 * 4;
    float* bcat = (float*)w;                              w += 3 * 256 * 4;
    float* Wf   = (float*)w;                              w += 2048;
    float* bfh2 = (float*)w;                              w += 256;
    float* degv = (float*)w;                              w += (size_t)NN * 4;
    int* deg    = (int*)w;                                w += (size_t)NN * 4;
    int* off    = (int*)w;                                w += (size_t)(NN + 4) * 4;
    int* cur    = (int*)w;                                w += (size_t)NN * 4;
    int* ssrc   = (int*)w;                                w += (size_t)NE * 4;
    int* part   = (int*)w;                                w += 1024;

    const int B256 = 256;
    int gN = (NN + B256 - 1) / B256;
    int gE = (NE + B256 - 1) / B256;
    int gGemm = (NN + 63) / 64;   // 782
    int gAgg = NN / 4;            // 12500

    // ---- CSR by dst ----
    k_zero_int<<<gN, B256, 0, stream>>>(deg, NN);
    k_count<<<gE, B256, 0, stream>>>(ei, deg);
    k_scan1<<<SCAN_B, B256, 0, stream>>>(deg, off, part, degv);
    k_scan2<<<1, B256, 0, stream>>>(part, off);
    k_scan3<<<SCAN_B, B256, 0, stream>>>(off, part, cur);
    k_scatter<<<gE, B256, 0, stream>>>(ei, cur, ssrc);

    // ---- all weight prep in one launch ----
    k_prep<<<770, 128, 0, stream>>>(W1_0, W2_0, b2_0, W1s, b1s, W2s, b2s, Wo,
                                    Wc0, Wt_all, dvec, bcat, Wf, bfh2);

    // ---- layer 0 ----
    k_l0<<<NN, 256, 0, stream>>>(x, Wc0, b1_0, AB);
    k_agg<false><<<gAgg, B256, 0, stream>>>(AB, off, ssrc, T, Wf, bfh2, bo, out);

    // ---- fused layers g = 0..2: AB = -2log2e*(T @ Wt_g + deg*dvec_g + bcat_g) ----
    for (int g = 0; g < 3; g++) {
        k_gemm_ab<<<gGemm, B256, 0, stream>>>(T, Wt_all + (size_t)g * 32768,
                                              dvec + g * 256, bcat + g * 256, degv, AB);
        if (g < 2)
            k_agg<false><<<gAgg, B256, 0, stream>>>(AB, off, ssrc, T, Wf, bfh2, bo, out);
        else
            k_agg<true><<<gAgg, B256, 0, stream>>>(AB, off, ssrc, T, Wf, bfh2, bo, out);
    }
}

// Round 8
// 391.359 us; speedup vs baseline: 2.5538x; 1.0496x over previous
//
#include <hip/hip_runtime.h>
#include <hip/hip_fp16.h>
#include <math.h>

#define NN 50000
#define NE 600000
#define IN_DIM 7
#define SCAN_B ((NN + 255) / 256)   // 196 blocks

// agg stores AB pre-scaled by -2*log2(e) so tanh(a+b) = 2*rcp(1+exp2(a'+b')) - 1
#define NEG2LOG2E -2.8853900817779268f

typedef _Float16 half8 __attribute__((ext_vector_type(8)));
typedef short short8 __attribute__((ext_vector_type(8)));
typedef float f32x4  __attribute__((ext_vector_type(4)));
typedef unsigned int uint;

#if __has_builtin(__builtin_amdgcn_exp2f)
#define EXP2F(x) __builtin_amdgcn_exp2f(x)
#else
#define EXP2F(x) __expf(0.6931471805599453f * (x))
#endif

// ---------------- CSR build ----------------

__global__ void k_zero_int(int* __restrict__ p, int n) {
    int i = blockIdx.x * blockDim.x + threadIdx.x;
    if (i < n) p[i] = 0;
}

__global__ void k_count(const int* __restrict__ ei, int* __restrict__ deg) {
    int e = blockIdx.x * blockDim.x + threadIdx.x;
    if (e < NE) atomicAdd(&deg[ei[NE + e]], 1);
}

__global__ __launch_bounds__(256) void k_scan1(const int* __restrict__ deg,
                                               int* __restrict__ off,
                                               int* __restrict__ part,
                                               float* __restrict__ degv) {
    __shared__ int s[256];
    int i = blockIdx.x * 256 + threadIdx.x;
    int v = (i < NN) ? deg[i] : 0;
    s[threadIdx.x] = v;
    __syncthreads();
    #pragma unroll
    for (int o = 1; o < 256; o <<= 1) {
        int t = (threadIdx.x >= o) ? s[threadIdx.x - o] : 0;
        __syncthreads();
        s[threadIdx.x] += t;
        __syncthreads();
    }
    if (i < NN) { off[i] = s[threadIdx.x] - v; degv[i] = (float)v; }
    if (threadIdx.x == 255) part[blockIdx.x] = s[255];
}

__global__ __launch_bounds__(256) void k_scan2(int* __restrict__ part,
                                               int* __restrict__ off) {
    __shared__ int s[256];
    int v = (threadIdx.x < SCAN_B) ? part[threadIdx.x] : 0;
    s[threadIdx.x] = v;
    __syncthreads();
    #pragma unroll
    for (int o = 1; o < 256; o <<= 1) {
        int t = (threadIdx.x >= o) ? s[threadIdx.x - o] : 0;
        __syncthreads();
        s[threadIdx.x] += t;
        __syncthreads();
    }
    if (threadIdx.x < SCAN_B) part[threadIdx.x] = s[threadIdx.x] - v;
    if (threadIdx.x == 255) off[NN] = s[255];
}

__global__ __launch_bounds__(256) void k_scan3(int* __restrict__ off,
                                               const int* __restrict__ part,
                                               int* __restrict__ cur) {
    int i = blockIdx.x * 256 + threadIdx.x;
    if (i < NN) {
        int v = off[i] + part[blockIdx.x];
        off[i] = v;
        cur[i] = v;
    }
}

// ssrc stores src*32 (uint4-stride units) so agg's gather address chain is add-only
__global__ void k_scatter(const int* __restrict__ ei, int* __restrict__ cur,
                          int* __restrict__ ssrc) {
    int e = blockIdx.x * blockDim.x + threadIdx.x;
    if (e < NE) {
        int s = ei[e];
        int d = ei[NE + e];
        int pos = atomicAdd(&cur[d], 1);
        ssrc[pos] = s * 32;
    }
}

// ---------------- one-shot weight prep ----------------

__global__ __launch_bounds__(128) void k_prep(const float* __restrict__ W1_0,
                                              const float* __restrict__ W2_0,
                                              const float* __restrict__ b2_0,
                                              const float* __restrict__ W1s,
                                              const float* __restrict__ b1s,
                                              const float* __restrict__ W2s,
                                              const float* __restrict__ b2s,
                                              const float* __restrict__ Wo,
                                              float* __restrict__ Wc0,
                                              _Float16* __restrict__ Wt_all,
                                              float* __restrict__ dvec_all,
                                              float* __restrict__ bcat_all,
                                              float* __restrict__ Wf,
                                              float* __restrict__ bfh2) {
    int b = blockIdx.x;
    int t = threadIdx.x;
    if (b < 768) {
        int g = b >> 8, c = b & 255;
        const float* W1g = W1s + (size_t)g * 256 * 128;
        const float* b1g = b1s + (size_t)g * 128;
        const float* W2p = (g == 0) ? W2_0 : W2s + (size_t)(g - 1) * 128 * 128;
        const float* b2p = (g == 0) ? b2_0 : b2s + (size_t)(g - 1) * 128;
        __shared__ float wc[128];
        int m = t;
        float v;
        if (c < 128) v = W1g[m * 128 + c] - W1g[(m + 128) * 128 + c];
        else         v = W1g[(m + 128) * 128 + (c - 128)];
        wc[m] = v;
        __syncthreads();
        int k = t;
        float acc = 0.f;
        #pragma unroll 8
        for (int mm = 0; mm < 128; mm++) acc += W2p[k * 128 + mm] * wc[mm];
        Wt_all[(size_t)g * 32768 + c * 128 + k] = (_Float16)acc;
        if (t == 0) {
            float dacc = 0.f;
            for (int mm = 0; mm < 128; mm++) dacc += b2p[mm] * wc[mm];
            dvec_all[g * 256 + c] = dacc;
            bcat_all[g * 256 + c] = (c < 128) ? b1g[c] : 0.f;
        }
    } else if (b == 768) {
        for (int idx = t; idx < IN_DIM * 256; idx += 128) {
            int k = idx >> 8, c = idx & 255;
            float v;
            if (c < 128) v = W1_0[k * 128 + c] - W1_0[(k + IN_DIM) * 128 + c];
            else         v = W1_0[(k + IN_DIM) * 128 + (c - 128)];
            Wc0[idx] = v;
        }
    } else {
        const float* W2l = W2s + (size_t)2 * 128 * 128;
        const float* b2l = b2s + (size_t)2 * 128;
        int k = t;
        #pragma unroll
        for (int r = 0; r < 3; r++) {
            float acc = 0.f;
            for (int m = 0; m < 128; m++) acc += W2l[k * 128 + m] * Wo[m * 3 + r];
            Wf[k * 3 + r] = acc;
        }
        __syncthreads();
        if (k < 3) {
            float acc = 0.f;
            for (int m = 0; m < 128; m++) acc += b2l[m] * Wo[m * 3 + k];
            float wfsum = 0.f;
            for (int m = 0; m < 128; m++) wfsum += Wf[m * 3 + k];
            bfh2[k] = acc - wfsum;
        }
    }
}

// ---------------- layer-0: AB = (-2log2e)*(x @ Wc0 + b1cat) (fp16 out) ----------------

__global__ __launch_bounds__(256) void k_l0(const float* __restrict__ x,
                                            const float* __restrict__ Wc,
                                            const float* __restrict__ b1,
                                            _Float16* __restrict__ AB) {
    int i = blockIdx.x;
    int c = threadIdx.x;
    __shared__ float xs[IN_DIM];
    if (threadIdx.x < IN_DIM) xs[threadIdx.x] = x[i * IN_DIM + threadIdx.x];
    __syncthreads();
    float acc = (c < 128) ? b1[c] : 0.f;
    #pragma unroll
    for (int k = 0; k < IN_DIM; k++) acc += xs[k] * Wc[k * 256 + c];
    AB[i * 256 + c] = (_Float16)(NEG2LOG2E * acc);
}

// ---------------- fused MFMA GEMM: AB = (-2log2e)*(T @ Wt^T + deg*dvec + bcat) ----------------

__global__ __launch_bounds__(256) void k_gemm_ab(const _Float16* __restrict__ Tin,
                                                 const _Float16* __restrict__ Wt,
                                                 const float* __restrict__ dvec,
                                                 const float* __restrict__ bcat,
                                                 const float* __restrict__ degv,
                                                 _Float16* __restrict__ ABout) {
    __shared__ short Tl[64 * 136];   // +8 pad -> conflict-free ds_read_b128
    __shared__ float degl[64];
    int t = threadIdx.x;
    int m0 = blockIdx.x * 64;
    const short* Ts = (const short*)Tin;
    const short* Ws = (const short*)Wt;

    #pragma unroll
    for (int it = 0; it < 4; it++) {
        int idx = t + it * 256;
        int row = idx >> 4, seg = idx & 15;
        int gr = m0 + row;
        short8 v = {0, 0, 0, 0, 0, 0, 0, 0};
        if (gr < NN) v = *(const short8*)&Ts[gr * 128 + seg * 8];
        *(short8*)&Tl[row * 136 + seg * 8] = v;
    }
    if (t < 64) degl[t] = (m0 + t < NN) ? degv[m0 + t] : 0.f;
    __syncthreads();

    int lane = t & 63;
    int wv = t >> 6;
    int l15 = lane & 15, quad = lane >> 4;

    half8 a[4][4];
    #pragma unroll
    for (int rt = 0; rt < 4; rt++)
        #pragma unroll
        for (int ks = 0; ks < 4; ks++) {
            short8 s8 = *(const short8*)&Tl[(rt * 16 + l15) * 136 + ks * 32 + quad * 8];
            a[rt][ks] = __builtin_bit_cast(half8, s8);
        }

    int c0 = wv * 64;
    #pragma unroll
    for (int ct = 0; ct < 4; ct++) {
        int ccol = c0 + ct * 16 + l15;
        half8 b[4];
        #pragma unroll
        for (int ks = 0; ks < 4; ks++) {
            short8 s8 = *(const short8*)&Ws[ccol * 128 + ks * 32 + quad * 8];
            b[ks] = __builtin_bit_cast(half8, s8);
        }
        float bc = bcat[ccol], dv = dvec[ccol];
        #pragma unroll
        for (int rt = 0; rt < 4; rt++) {
            f32x4 acc = {0.f, 0.f, 0.f, 0.f};
            #pragma unroll
            for (int ks = 0; ks < 4; ks++)
                acc = __builtin_amdgcn_mfma_f32_16x16x32_f16(a[rt][ks], b[ks], acc, 0, 0, 0);
            #pragma unroll
            for (int r = 0; r < 4; r++) {
                int row = rt * 16 + quad * 4 + r;
                int grow = m0 + row;
                if (grow < NN) {
                    float v = acc[r] + degl[row] * dv + bc;
                    ABout[(size_t)grow * 256 + ccol] = (_Float16)(NEG2LOG2E * v);
                }
            }
        }
    }
}

// ---------------- aggregation (+ optional fused head) ----------------
// One wave per node. 16 lanes per edge (8 channels each, uint4 = 8 fp16),
// 4 edge-groups per wave => 4 edges per batch. 16-edge super-iterations keep
// FOUR batch gathers in flight per lane (deep prefetch to cover ~500cy L3).
// Clamped duplicate loads in the tail are same-address (L1 broadcast) and the
// consume guard skips their VALU.

template <bool HEAD>
__global__ __launch_bounds__(256) void k_agg(const _Float16* __restrict__ AB,
                                             const int* __restrict__ off,
                                             const int* __restrict__ ssrc,
                                             _Float16* __restrict__ T,
                                             const float* __restrict__ Wf,
                                             const float* __restrict__ bfh2,
                                             const float* __restrict__ bo,
                                             float* __restrict__ out) {
    int t = threadIdx.x;
    int i = blockIdx.x * 4 + (t >> 6);   // one wave per node
    int lane = t & 63;
    int q = lane & 15;                   // channel octet: channels 8q..8q+7
    int g = lane >> 4;                   // edge group 0..3
    const uint4* AB4 = (const uint4*)AB; // 32 uint4 per row: A=[0,16), B=[16,32)

    uint4 av = AB4[(size_t)i * 32 + q];
    uint ah[4] = {av.x, av.y, av.z, av.w};
    int s0 = off[i], s1 = off[i + 1];
    float acc[8];
    #pragma unroll
    for (int k = 0; k < 8; k++) acc[k] = 0.f;

    int qoff = 16 + q;   // uint4 offset within B half-row
    uint4 bv[4];

    // issue a clamped batch gather for edges [SB, SB+4)
    #define LOAD_BATCH(D, SB)                                     \
        {                                                         \
            int ss = (SB) + g;                                    \
            int sc = (ss < s1) ? ss : (s1 - 1);                   \
            bv[D] = AB4[(size_t)(uint)ssrc[sc] + qoff];           \
        }
    // consume batch D covering edges [SB, SB+4)
    #define CONSUME(D, SB)                                        \
        if ((SB) + g < s1) {                                      \
            uint bh[4] = {bv[D].x, bv[D].y, bv[D].z, bv[D].w};    \
            _Pragma("unroll")                                     \
            for (int k = 0; k < 4; k++) {                         \
                __half2 ua = *reinterpret_cast<__half2*>(&ah[k]); \
                __half2 ub = *reinterpret_cast<__half2*>(&bh[k]); \
                __half2 u2 = __hadd2(ua, ub);                     \
                float2 uf = __half22float2(u2);                   \
                float e0 = EXP2F(uf.x);                           \
                float e1 = EXP2F(uf.y);                           \
                acc[2 * k + 0] += __builtin_amdgcn_rcpf(1.f + e0);\
                acc[2 * k + 1] += __builtin_amdgcn_rcpf(1.f + e1);\
            }                                                     \
        }

    if (s0 < s1) {
        // prologue: 4 batches in flight
        LOAD_BATCH(0, s0)
        LOAD_BATCH(1, s0 + 4)
        LOAD_BATCH(2, s0 + 8)
        LOAD_BATCH(3, s0 + 12)
        // steady state: 16-edge super-iterations
        int s = s0;
        for (; s + 16 < s1; s += 16) {
            CONSUME(0, s)      LOAD_BATCH(0, s + 16)
            CONSUME(1, s + 4)  LOAD_BATCH(1, s + 20)
            CONSUME(2, s + 8)  LOAD_BATCH(2, s + 24)
            CONSUME(3, s + 12) LOAD_BATCH(3, s + 28)
        }
        // epilogue: consume remaining in-flight batches
        CONSUME(0, s)
        CONSUME(1, s + 4)
        CONSUME(2, s + 8)
        CONSUME(3, s + 12)
    }
    #undef LOAD_BATCH
    #undef CONSUME

    if (!HEAD) {
        // reduce the 4 edge-groups; lanes 0-15 write 8 channels (uint4)
        #pragma unroll
        for (int k = 0; k < 8; k++) {
            acc[k] += __shfl_xor(acc[k], 16);
            acc[k] += __shfl_xor(acc[k], 32);
        }
        if (lane < 16) {
            float degf = (float)(s1 - s0);
            uint4 pv;
            uint* pu = reinterpret_cast<uint*>(&pv);
            #pragma unroll
            for (int k = 0; k < 4; k++) {
                __half2 p = __float22half2_rn(make_float2(
                    2.f * acc[2 * k + 0] - degf, 2.f * acc[2 * k + 1] - degf));
                pu[k] = *reinterpret_cast<uint*>(&p);
            }
            ((uint4*)T)[(size_t)i * 16 + q] = pv;
        }
    } else {
        int ch = 8 * q;
        float p0 = 0.f, p1 = 0.f, p2 = 0.f;
        #pragma unroll
        for (int k = 0; k < 8; k++) {
            float v = acc[k];
            p0 += v * Wf[(ch + k) * 3 + 0];
            p1 += v * Wf[(ch + k) * 3 + 1];
            p2 += v * Wf[(ch + k) * 3 + 2];
        }
        #pragma unroll
        for (int o = 32; o > 0; o >>= 1) {
            p0 += __shfl_down(p0, o);
            p1 += __shfl_down(p1, o);
            p2 += __shfl_down(p2, o);
        }
        if (lane == 0) {
            float degf = (float)(s1 - s0);
            out[i * 3 + 0] = 2.f * p0 + degf * bfh2[0] + bo[0];
            out[i * 3 + 1] = 2.f * p1 + degf * bfh2[1] + bo[1];
            out[i * 3 + 2] = 2.f * p2 + degf * bfh2[2] + bo[2];
        }
    }
}

// ---------------- host ----------------

extern "C" void kernel_launch(void* const* d_in, const int* in_sizes, int n_in,
                              void* d_out, int out_size, void* d_ws, size_t ws_size,
                              hipStream_t stream) {
    const float* x    = (const float*)d_in[0];
    const int*   ei   = (const int*)d_in[1];
    const float* W1_0 = (const float*)d_in[2];
    const float* b1_0 = (const float*)d_in[3];
    const float* W2_0 = (const float*)d_in[4];
    const float* b2_0 = (const float*)d_in[5];
    const float* W1s  = (const float*)d_in[6];
    const float* b1s  = (const float*)d_in[7];
    const float* W2s  = (const float*)d_in[8];
    const float* b2s  = (const float*)d_in[9];
    const float* Wo   = (const float*)d_in[10];
    const float* bo   = (const float*)d_in[11];
    float* out = (float*)d_out;

    char* w = (char*)d_ws;
    _Float16* AB = (_Float16*)w;                          w += (size_t)NN * 256 * 2;   // 25.6 MB
    _Float16* T  = (_Float16*)w;                          w += (size_t)NN * 128 * 2;   // 12.8 MB
    float* Wc0  = (float*)w;                              w += IN_DIM * 256 * 4;
    _Float16* Wt_all = (_Float16*)w;                      w += 3 * 256 * 128 * 2;
    float* dvec = (float*)w;                              w += 3 * 256 * 4;
    float* bcat = (float*)w;                              w += 3 * 256 * 4;
    float* Wf   = (float*)w;                              w += 2048;
    float* bfh2 = (float*)w;                              w += 256;
    float* degv = (float*)w;                              w += (size_t)NN * 4;
    int* deg    = (int*)w;                                w += (size_t)NN * 4;
    int* off    = (int*)w;                                w += (size_t)(NN + 4) * 4;
    int* cur    = (int*)w;                                w += (size_t)NN * 4;
    int* ssrc   = (int*)w;                                w += (size_t)NE * 4;
    int* part   = (int*)w;                                w += 1024;

    const int B256 = 256;
    int gN = (NN + B256 - 1) / B256;
    int gE = (NE + B256 - 1) / B256;
    int gGemm = (NN + 63) / 64;   // 782
    int gAgg = NN / 4;            // 12500

    // ---- CSR by dst ----
    k_zero_int<<<gN, B256, 0, stream>>>(deg, NN);
    k_count<<<gE, B256, 0, stream>>>(ei, deg);
    k_scan1<<<SCAN_B, B256, 0, stream>>>(deg, off, part, degv);
    k_scan2<<<1, B256, 0, stream>>>(part, off);
    k_scan3<<<SCAN_B, B256, 0, stream>>>(off, part, cur);
    k_scatter<<<gE, B256, 0, stream>>>(ei, cur, ssrc);

    // ---- all weight prep in one launch ----
    k_prep<<<770, 128, 0, stream>>>(W1_0, W2_0, b2_0, W1s, b1s, W2s, b2s, Wo,
                                    Wc0, Wt_all, dvec, bcat, Wf, bfh2);

    // ---- layer 0 ----
    k_l0<<<NN, 256, 0, stream>>>(x, Wc0, b1_0, AB);
    k_agg<false><<<gAgg, B256, 0, stream>>>(AB, off, ssrc, T, Wf, bfh2, bo, out);

    // ---- fused layers g = 0..2: AB = -2log2e*(T @ Wt_g + deg*dvec_g + bcat_g) ----
    for (int g = 0; g < 3; g++) {
        k_gemm_ab<<<gGemm, B256, 0, stream>>>(T, Wt_all + (size_t)g * 32768,
                                              dvec + g * 256, bcat + g * 256, degv, AB);
        if (g < 2)
            k_agg<false><<<gAgg, B256, 0, stream>>>(AB, off, ssrc, T, Wf, bfh2, bo, out);
        else
            k_agg<true><<<gAgg, B256, 0, stream>>>(AB, off, ssrc, T, Wf, bfh2, bo, out);
    }
}